// Round 11
// baseline (617.150 us; speedup 1.0000x reference)
//
#include <hip/hip_runtime.h>

typedef unsigned short u16;
typedef unsigned int u32;
typedef unsigned long long u64;

#define E_TOT 202752   // B*N0*DEG = 32*1584*4
#define NMAX  50688    // B*N0
#define HEADS 4
#define B_    32
#define MAXDEG 32      // Poisson(4) in-degree: P(>=32) ~ 1e-18/node — safe bucket

#define CDIV(a,b) (((a)+(b)-1)/(b))

// order-preserving float->uint map (monotonic); code 0 is below any real float's code
__device__ __forceinline__ u32 ford(float f) {
  u32 u = __float_as_uint(f);
  return (u & 0x80000000u) ? ~u : (u | 0x80000000u);
}
__device__ __forceinline__ float ford_inv(u32 u) {
  u32 b = (u & 0x80000000u) ? (u ^ 0x80000000u) : ~u;
  return __uint_as_float(b);
}

// edge arrays + CSR for layer 0 in one pass (cnt pre-zeroed)
__global__ void k_edge_init_csr(const int* __restrict__ ei, int* __restrict__ src,
                                int* __restrict__ dst, int* __restrict__ em,
                                int* __restrict__ cnt, int* __restrict__ csr) {
  int e = blockIdx.x * blockDim.x + threadIdx.x;
  if (e >= E_TOT) return;
  int s = ei[e], d = ei[E_TOT + e];
  src[e] = s;
  dst[e] = d;
  em[e] = 1;
  int pos = atomicAdd(&cnt[d], 1);
  if (pos < MAXDEG) csr[d * MAXDEG + pos] = e;
}

// ---------- node transform, 8 nodes/block, XCD-swizzled so graph g lands on XCD g%8 ----
// grid = 32 * NB blocks, NB = ceil(nper/8)
template <int FIN>
__global__ void k_transform_t(const float* __restrict__ hin,
                              const float* __restrict__ Wl, const float* __restrict__ bl,
                              const float* __restrict__ Wr, const float* __restrict__ br,
                              float* __restrict__ xl, float* __restrict__ xr,
                              int nper, int NB) {
  __shared__ float xs[8][FIN];
  int b = blockIdx.x;
  int xcd = b & 7, slot = b >> 3;
  int g = xcd + 8 * (slot / NB);
  int jb = slot % NB;
  int base = jb * 8;                          // local node base within graph
  int cnt8 = nper - base; if (cnt8 > 8) cnt8 = 8;
  int n0 = g * nper + base;
  int j = threadIdx.x;                        // 256 threads
  for (int t = j; t < cnt8 * FIN; t += 256)
    xs[t >> (FIN == 32 ? 5 : 6)][t & (FIN - 1)] =
        hin[(size_t)(n0 + (t >> (FIN == 32 ? 5 : 6))) * FIN + (t & (FIN - 1))];
  __syncthreads();
  float al[8], ar[8];
  float blv = bl[j], brv = br[j];
#pragma unroll
  for (int t = 0; t < 8; ++t) { al[t] = blv; ar[t] = brv; }
  for (int i = 0; i < FIN; ++i) {
    float wl = Wl[i * 256 + j], wr = Wr[i * 256 + j];
#pragma unroll
    for (int t = 0; t < 8; ++t) {
      float xv = (t < cnt8) ? xs[t][i] : 0.f;
      al[t] += xv * wl;
      ar[t] += xv * wr;
    }
  }
  for (int t = 0; t < cnt8; ++t) {
    xl[(size_t)(n0 + t) * 256 + j] = al[t];
    xr[(size_t)(n0 + t) * 256 + j] = ar[t];
  }
}

// ---------- fused GATv2 per dst node, XCD-swizzled; 4 nodes (waves)/block ----------
// grid = 32 * NB blocks, NB = ceil(nper/4); lane = (head h = lane>>4, chan-group cg)
__global__ void k_gat_fused(const int* __restrict__ srcv, const int* __restrict__ cnt,
                            const int* __restrict__ csr, const float* __restrict__ ea,
                            const float* __restrict__ We, const float* __restrict__ att,
                            const float* __restrict__ xl, const float* __restrict__ xr,
                            const float* __restrict__ bias, const float* __restrict__ pwv,
                            float* __restrict__ out, float* __restrict__ sc,
                            int nper, int NB) {
  int b = blockIdx.x;
  int xcd = b & 7, slot = b >> 3;
  int g = xcd + 8 * (slot / NB);
  int ln = (slot % NB) * 4 + (threadIdx.x >> 6);   // local node in graph
  if (ln >= nper) return;
  int n = g * nper + ln;
  int lane = threadIdx.x & 63;
  int cg = lane & 15;
  int cb = (lane >> 4) * 64 + cg * 4;              // this lane's 4 channels
  int deg = min(cnt[n], MAXDEG);
  // lane-parallel prefetch of edge ids + src ids (breaks the per-edge dep chain)
  int e_l = 0, s_l = 0;
  if (lane < deg) { e_l = csr[n * MAXDEG + lane]; s_l = srcv[e_l]; }
  float4 xd4 = *(const float4*)(xr + (size_t)n * 256 + cb);
  float4 at4 = *(const float4*)(att + cb);
  float4 w0 = *(const float4*)(We + 0 * 256 + cb);
  float4 w1 = *(const float4*)(We + 1 * 256 + cb);
  float4 w2 = *(const float4*)(We + 2 * 256 + cb);
  float4 w3 = *(const float4*)(We + 3 * 256 + cb);
  float4 w4_ = *(const float4*)(We + 4 * 256 + cb);
  float4 w5 = *(const float4*)(We + 5 * 256 + cb);
  float4 w6 = *(const float4*)(We + 6 * 256 + cb);
  float4 w7 = *(const float4*)(We + 7 * 256 + cb);
  float m = -INFINITY, l = 0.f;
  float ox = 0.f, oy = 0.f, oz = 0.f, ow = 0.f;
  for (int i0 = 0; i0 < deg; i0 += 4) {
    int c0 = deg - i0; if (c0 > 4) c0 = 4;         // wave-uniform
    float4 xs[4], a0[4], a1[4];
#pragma unroll
    for (int j = 0; j < 4; ++j) {
      int idx = (j < c0) ? (i0 + j) : i0;          // clamp to a safe slot
      int e = __shfl(e_l, idx, 64);
      int s = __shfl(s_l, idx, 64);
      xs[j] = *(const float4*)(xl + (size_t)s * 256 + cb);   // independent, all in flight
      a0[j] = *(const float4*)(ea + (size_t)e * 8);
      a1[j] = *(const float4*)(ea + (size_t)e * 8 + 4);
    }
#pragma unroll
    for (int j = 0; j < 4; ++j) {
      if (j < c0) {
        float e0 = a0[j].x * w0.x + a0[j].y * w1.x + a0[j].z * w2.x + a0[j].w * w3.x
                 + a1[j].x * w4_.x + a1[j].y * w5.x + a1[j].z * w6.x + a1[j].w * w7.x;
        float e1 = a0[j].x * w0.y + a0[j].y * w1.y + a0[j].z * w2.y + a0[j].w * w3.y
                 + a1[j].x * w4_.y + a1[j].y * w5.y + a1[j].z * w6.y + a1[j].w * w7.y;
        float e2 = a0[j].x * w0.z + a0[j].y * w1.z + a0[j].z * w2.z + a0[j].w * w3.z
                 + a1[j].x * w4_.z + a1[j].y * w5.z + a1[j].z * w6.z + a1[j].w * w7.z;
        float e3 = a0[j].x * w0.w + a0[j].y * w1.w + a0[j].z * w2.w + a0[j].w * w3.w
                 + a1[j].x * w4_.w + a1[j].y * w5.w + a1[j].z * w6.w + a1[j].w * w7.w;
        float m0 = xs[j].x + xd4.x + e0; m0 = (m0 >= 0.f) ? m0 : 0.2f * m0;  // leaky 0.2
        float m1 = xs[j].y + xd4.y + e1; m1 = (m1 >= 0.f) ? m1 : 0.2f * m1;
        float m2 = xs[j].z + xd4.z + e2; m2 = (m2 >= 0.f) ? m2 : 0.2f * m2;
        float m3 = xs[j].w + xd4.w + e3; m3 = (m3 >= 0.f) ? m3 : 0.2f * m3;
        float v = at4.x * m0 + at4.y * m1 + at4.z * m2 + at4.w * m3;
        v += __shfl_xor(v, 1, 64);
        v += __shfl_xor(v, 2, 64);
        v += __shfl_xor(v, 4, 64);
        v += __shfl_xor(v, 8, 64);     // all 16 head-lanes hold the head logit
        float nm = fmaxf(m, v);
        float scale = __expf(m - nm);  // exp(-inf - x) = 0 handles first edge
        float p = __expf(v - nm);
        ox = ox * scale + p * xs[j].x;
        oy = oy * scale + p * xs[j].y;
        oz = oz * scale + p * xs[j].z;
        ow = ow * scale + p * xs[j].w;
        l = l * scale + p;
        m = nm;
      }
    }
  }
  // per-head y = O/den, then 0.25 * head-sum  (deg==0 -> l=0 -> y=0, matches ref)
  float inv = 0.25f / fmaxf(l, 1e-16f);
  float r0 = ox * inv, r1 = oy * inv, r2 = oz * inv, r3 = ow * inv;
  r0 += __shfl_xor(r0, 16, 64); r0 += __shfl_xor(r0, 32, 64);
  r1 += __shfl_xor(r1, 16, 64); r1 += __shfl_xor(r1, 32, 64);
  r2 += __shfl_xor(r2, 16, 64); r2 += __shfl_xor(r2, 32, 64);
  r3 += __shfl_xor(r3, 16, 64); r3 += __shfl_xor(r3, 32, 64);
  float4 bi4 = *(const float4*)(bias + cg * 4);
  r0 = fmaxf(r0 + bi4.x, 0.f); r1 = fmaxf(r1 + bi4.y, 0.f);
  r2 = fmaxf(r2 + bi4.z, 0.f); r3 = fmaxf(r3 + bi4.w, 0.f);
  if (lane < 16) *(float4*)(out + (size_t)n * 64 + cg * 4) = float4{r0, r1, r2, r3};
  // topk score: s = tanh(h.w / ||w||)
  float4 pw4 = *(const float4*)(pwv + cg * 4);
  float dot = r0 * pw4.x + r1 * pw4.y + r2 * pw4.z + r3 * pw4.w;
  float wn = pw4.x * pw4.x + pw4.y * pw4.y + pw4.z * pw4.z + pw4.w * pw4.w;
  dot += __shfl_xor(dot, 1, 64); wn += __shfl_xor(wn, 1, 64);
  dot += __shfl_xor(dot, 2, 64); wn += __shfl_xor(wn, 2, 64);
  dot += __shfl_xor(dot, 4, 64); wn += __shfl_xor(wn, 4, 64);
  dot += __shfl_xor(dot, 8, 64); wn += __shfl_xor(wn, 8, 64);
  if (lane == 0) sc[n] = tanhf(dot / sqrtf(wn));
}

// stable descending sort per graph — u64 keys (ford(score)<<32 | ~idx), bitonic <=2048
__global__ __launch_bounds__(1024) void k_topk(const float* __restrict__ s, int n_per,
                                               int k, int npad,
                                               int* __restrict__ perm, int* __restrict__ new_id) {
  __shared__ u64 kv[2048];
  int b = blockIdx.x, tid = threadIdx.x;
  int base = b * n_per;
  for (int i = tid; i < n_per; i += 1024) new_id[base + i] = -1;
  for (int i = tid; i < npad; i += 1024) {
    u32 sk = (i < n_per) ? ford(s[base + i]) : 0u;   // pad key 0: below every real code
    kv[i] = ((u64)sk << 32) | (u32)(0xFFFFFFFFu - (u32)i);   // tie -> lower idx first
  }
  __syncthreads();
  for (int kk = 2; kk <= npad; kk <<= 1) {
    for (int j = kk >> 1; j > 0; j >>= 1) {
      for (int i = tid; i < npad; i += 1024) {
        int ixj = i ^ j;
        if (ixj > i) {
          u64 a = kv[i], c = kv[ixj];
          bool after = a < c;                        // descending order
          bool doswap = ((i & kk) == 0) ? after : !after;
          if (doswap) { kv[i] = c; kv[ixj] = a; }
        }
      }
      __syncthreads();
    }
  }
  for (int r = tid; r < k; r += 1024) {
    int old = (int)(0xFFFFFFFFu - (u32)(kv[r] & 0xFFFFFFFFu));
    perm[b * k + r] = base + old;
    new_id[base + old] = b * k + r;
  }
}

__global__ void k_gather(const float* __restrict__ hin, const float* __restrict__ s,
                         const int* __restrict__ perm, float* __restrict__ hout, int n64) {
  int t = blockIdx.x * blockDim.x + threadIdx.x;
  if (t >= n64) return;
  int i = t >> 6, c = t & 63;
  int g = perm[i];
  hout[t] = hin[(size_t)g * 64 + c] * s[g];
}

// remap edges AND build next layer's CSR (cnt pre-zeroed)
__global__ void k_remap_csr(int* __restrict__ src, int* __restrict__ dst,
                            int* __restrict__ em, const int* __restrict__ new_id,
                            int* __restrict__ cnt, int* __restrict__ csr) {
  int e = blockIdx.x * blockDim.x + threadIdx.x;
  if (e >= E_TOT) return;
  int ns = new_id[src[e]], nd = new_id[dst[e]];
  int m = em[e] && ns >= 0 && nd >= 0;
  src[e] = m ? ns : 0;
  dst[e] = m ? nd : 0;
  em[e] = m;
  if (m) {
    int pos = atomicAdd(&cnt[nd], 1);
    if (pos < MAXDEG) csr[nd * MAXDEG + pos] = e;
  }
}

// chunked parallel readout: grid (B, 16), 256 thr
__global__ void k_readout_part(const float* __restrict__ h, int k,
                               float* __restrict__ rsum, u32* __restrict__ rmaxI) {
  __shared__ float ps[256], pm[256];
  int b = blockIdx.x, ch = blockIdx.y, t = threadIdx.x;
  int c = t & 63, rg = t >> 6;
  int rpc = (k + 15) >> 4;
  int start = ch * rpc, end = min(k, start + rpc);
  const float* hb = h + (size_t)b * k * 64;
  float sum = 0.f, mx = -INFINITY;
  for (int i = start + rg; i < end; i += 4) {
    float v = hb[(size_t)i * 64 + c];
    sum += v;
    mx = fmaxf(mx, v);
  }
  ps[t] = sum; pm[t] = mx;
  __syncthreads();
  if (t < 64) {
    float s4 = ps[t] + ps[t + 64] + ps[t + 128] + ps[t + 192];
    float m4 = fmaxf(fmaxf(pm[t], pm[t + 64]), fmaxf(pm[t + 128], pm[t + 192]));
    atomicAdd(&rsum[b * 64 + t], s4);
    atomicMax(&rmaxI[b * 64 + t], ford(m4));
  }
}

__global__ void k_readout_fin(const float* __restrict__ rsum, const u32* __restrict__ rmaxI,
                              int k, float* __restrict__ r) {
  int b = blockIdx.x, c = threadIdx.x;   // 128 threads
  if (c < 64) r[b * 128 + c] += rsum[b * 64 + c] / (float)k;
  else        r[b * 128 + c] += ford_inv(rmaxI[b * 64 + (c - 64)]);
}

__global__ void k_mlp(const float* __restrict__ r,
                      const float* __restrict__ W1, const float* __restrict__ b1,
                      const float* __restrict__ W2, const float* __restrict__ b2,
                      const float* __restrict__ W3, const float* __restrict__ b3,
                      float* __restrict__ out) {
  __shared__ float v0[128], v1[64], v2[64], lgts[16];
  int b = blockIdx.x, t = threadIdx.x;   // 64 threads
  v0[t] = r[b * 128 + t];
  v0[64 + t] = r[b * 128 + 64 + t];
  __syncthreads();
  float a = b1[t];
  for (int i = 0; i < 128; ++i) a += v0[i] * W1[i * 64 + t];
  v1[t] = fmaxf(a, 0.f);
  __syncthreads();
  a = b2[t];
  for (int i = 0; i < 64; ++i) a += v1[i] * W2[i * 64 + t];
  v2[t] = fmaxf(a, 0.f);
  __syncthreads();
  if (t < 16) {
    a = b3[t];
    for (int i = 0; i < 64; ++i) a += v2[i] * W3[i * 16 + t];
    lgts[t] = a;
  }
  __syncthreads();
  if (t == 0) {
    float m = lgts[0];
    for (int j = 1; j < 16; ++j) m = fmaxf(m, lgts[j]);
    float ex[16], sum = 0.f;
    for (int j = 0; j < 16; ++j) { ex[j] = expf(lgts[j] - m); sum += ex[j]; }
    for (int j = 0; j < 16; ++j) out[b * 16 + j] = ex[j] / sum;
  }
}

extern "C" void kernel_launch(void* const* d_in, const int* in_sizes, int n_in,
                              void* d_out, int out_size, void* d_ws, size_t ws_size,
                              hipStream_t stream) {
  (void)in_sizes; (void)n_in; (void)out_size; (void)ws_size;
  const float* x  = (const float*)d_in[0];      // [NMAX, 32] f32
  const float* ea = (const float*)d_in[1];      // [E, 8]     f32
  const int*   ei = (const int*)d_in[2];        // [2, E]

  const float *gWl[3], *gbl[3], *gWr[3], *gbr[3], *gWe[3], *gatt[3], *gb[3], *pw[3];
  for (int l = 0; l < 3; ++l) {
    int p0 = 4 + 7 * l;
    gWl[l]  = (const float*)d_in[p0 + 0];
    gbl[l]  = (const float*)d_in[p0 + 1];
    gWr[l]  = (const float*)d_in[p0 + 2];
    gbr[l]  = (const float*)d_in[p0 + 3];
    gWe[l]  = (const float*)d_in[p0 + 4];
    gatt[l] = (const float*)d_in[p0 + 5];
    gb[l]   = (const float*)d_in[p0 + 6];
    pw[l]   = (const float*)d_in[25 + l];
  }
  const float* fc1W = (const float*)d_in[28];
  const float* fc1b = (const float*)d_in[29];
  const float* fc2W = (const float*)d_in[30];
  const float* fc2b = (const float*)d_in[31];
  const float* fc3W = (const float*)d_in[32];
  const float* fc3b = (const float*)d_in[33];

  // ---- workspace carve (~136.9 MB; fits per round-5 gate) ----
  char* w = (char*)d_ws;
  size_t off = 0;
  auto alloc = [&](size_t bytes) -> void* {
    void* p = w + off;
    off += (bytes + 255) & ~(size_t)255;
    return p;
  };
  float* hbuf = (float*)alloc((size_t)B_ * 1268 * 64 * 4); // pooled features (max K1)
  float* xl   = (float*)alloc((size_t)NMAX * 256 * 4);     // source transform [N,256]
  float* xr   = (float*)alloc((size_t)NMAX * 256 * 4);     // target transform [N,256]
  float* nacc = (float*)alloc((size_t)NMAX * 64 * 4);      // fused GAT output (pre-pool)
  int*   cnt  = (int*)alloc((size_t)NMAX * 4);             // CSR degree counters
  char*  rblk = (char*)alloc(32 * 128 * 4);                // [rsum 8KB][rmaxI 8KB], per layer
  float* rsum = (float*)rblk;
  u32*   rmaxI= (u32*)(rblk + 32 * 64 * 4);
  int*   csr  = (int*)alloc((size_t)NMAX * MAXDEG * 4);
  float* sbuf = (float*)alloc((size_t)NMAX * 4);
  float* rbuf = (float*)alloc(32 * 128 * 4);
  int* src    = (int*)alloc((size_t)E_TOT * 4);
  int* dst    = (int*)alloc((size_t)E_TOT * 4);
  int* em     = (int*)alloc((size_t)E_TOT * 4);
  int* new_id = (int*)alloc((size_t)NMAX * 4);
  int* perm   = (int*)alloc((size_t)32 * 1268 * 4);

  hipMemsetAsync(cnt, 0, (size_t)NMAX * 4, stream);
  k_edge_init_csr<<<CDIV(E_TOT, 256), 256, 0, stream>>>(ei, src, dst, em, cnt, csr);
  hipMemsetAsync(rbuf, 0, 32 * 128 * 4, stream);

  const int npers[3] = {1584, 1268, 1015};
  const int ks[3]    = {1268, 1015, 812};
  const int npads[3] = {2048, 2048, 1024};

  for (int l = 0; l < 3; ++l) {
    int nper = npers[l];
    int NBt = CDIV(nper, 8);                 // transform blocks per graph
    int NBg = CDIV(nper, 4);                 // gat blocks per graph
    const float* hin = (l == 0) ? x : hbuf;
    hipMemsetAsync(rblk, 0, 32 * 128 * 4, stream);
    if (l == 0)
      k_transform_t<32><<<32 * NBt, 256, 0, stream>>>(hin, gWl[l], gbl[l], gWr[l], gbr[l],
                                                      xl, xr, nper, NBt);
    else
      k_transform_t<64><<<32 * NBt, 256, 0, stream>>>(hin, gWl[l], gbl[l], gWr[l], gbr[l],
                                                      xl, xr, nper, NBt);
    k_gat_fused<<<32 * NBg, 256, 0, stream>>>(src, cnt, csr, ea, gWe[l], gatt[l],
                                              xl, xr, gb[l], pw[l], nacc, sbuf, nper, NBg);
    k_topk<<<32, 1024, 0, stream>>>(sbuf, nper, ks[l], npads[l], perm, new_id);
    k_gather<<<CDIV(B_ * ks[l] * 64, 256), 256, 0, stream>>>(nacc, sbuf, perm, hbuf,
                                                             B_ * ks[l] * 64);
    if (l < 2) {
      hipMemsetAsync(cnt, 0, (size_t)NMAX * 4, stream);
      k_remap_csr<<<CDIV(E_TOT, 256), 256, 0, stream>>>(src, dst, em, new_id, cnt, csr);
    }
    k_readout_part<<<dim3(32, 16), 256, 0, stream>>>(hbuf, ks[l], rsum, rmaxI);
    k_readout_fin<<<32, 128, 0, stream>>>(rsum, rmaxI, ks[l], rbuf);
  }
  k_mlp<<<32, 64, 0, stream>>>(rbuf, fc1W, fc1b, fc2W, fc2b, fc3W, fc3b, (float*)d_out);
}

// Round 12
// 614.848 us; speedup vs baseline: 1.0037x; 1.0037x over previous
//
#include <hip/hip_runtime.h>

typedef unsigned short u16;
typedef unsigned int u32;
typedef unsigned long long u64;

#define E_TOT 202752   // B*N0*DEG = 32*1584*4
#define NMAX  50688    // B*N0
#define HEADS 4
#define B_    32
#define MAXDEG 32      // Poisson(4) in-degree: P(>=32) ~ 1e-18/node — safe bucket

#define CDIV(a,b) (((a)+(b)-1)/(b))

// order-preserving float->uint map (monotonic); code 0 is below any real float's code
__device__ __forceinline__ u32 ford(float f) {
  u32 u = __float_as_uint(f);
  return (u & 0x80000000u) ? ~u : (u | 0x80000000u);
}
__device__ __forceinline__ float ford_inv(u32 u) {
  u32 b = (u & 0x80000000u) ? (u ^ 0x80000000u) : ~u;
  return __uint_as_float(b);
}

// edge arrays + CSR for layer 0 in one pass (cnt pre-zeroed)
__global__ void k_edge_init_csr(const int* __restrict__ ei, int* __restrict__ src,
                                int* __restrict__ dst, int* __restrict__ em,
                                int* __restrict__ cnt, int* __restrict__ csr) {
  int e = blockIdx.x * blockDim.x + threadIdx.x;
  if (e >= E_TOT) return;
  int s = ei[e], d = ei[E_TOT + e];
  src[e] = s;
  dst[e] = d;
  em[e] = 1;
  int pos = atomicAdd(&cnt[d], 1);
  if (pos < MAXDEG) csr[d * MAXDEG + pos] = e;
}

// ---------- node transform, 8 nodes/block, W columns reused in regs (round-10 form) ----
template <int FIN>
__global__ void k_transform_t(const float* __restrict__ hin,
                              const float* __restrict__ Wl, const float* __restrict__ bl,
                              const float* __restrict__ Wr, const float* __restrict__ br,
                              float* __restrict__ xl, float* __restrict__ xr) {
  __shared__ float xs[8][FIN];
  int n0 = blockIdx.x * 8, j = threadIdx.x;   // 256 threads
  for (int t = j; t < 8 * FIN; t += 256)
    xs[t >> (FIN == 32 ? 5 : 6)][t & (FIN - 1)] =
        hin[(size_t)(n0 + (t >> (FIN == 32 ? 5 : 6))) * FIN + (t & (FIN - 1))];
  __syncthreads();
  float al[8], ar[8];
  float blv = bl[j], brv = br[j];
#pragma unroll
  for (int t = 0; t < 8; ++t) { al[t] = blv; ar[t] = brv; }
  for (int i = 0; i < FIN; ++i) {
    float wl = Wl[i * 256 + j], wr = Wr[i * 256 + j];
#pragma unroll
    for (int t = 0; t < 8; ++t) {
      float xv = xs[t][i];
      al[t] += xv * wl;
      ar[t] += xv * wr;
    }
  }
#pragma unroll
  for (int t = 0; t < 8; ++t) {
    xl[(size_t)(n0 + t) * 256 + j] = al[t];
    xr[(size_t)(n0 + t) * 256 + j] = ar[t];
  }
}

// ---------- fused GATv2 per dst node, XCD-swizzled, batched online softmax ----------
// grid = 32 * NB blocks, NB = ceil(nper/4); lane = (head h = lane>>4, chan-group cg)
__global__ __launch_bounds__(256, 4)
void k_gat_fused(const int* __restrict__ srcv, const int* __restrict__ cnt,
                 const int* __restrict__ csr, const float* __restrict__ ea,
                 const float* __restrict__ We, const float* __restrict__ att,
                 const float* __restrict__ xl, const float* __restrict__ xr,
                 const float* __restrict__ bias, const float* __restrict__ pwv,
                 float* __restrict__ out, float* __restrict__ sc,
                 int nper, int NB) {
  int b = blockIdx.x;
  int xcd = b & 7, slot = b >> 3;
  int g = xcd + 8 * (slot / NB);
  int ln = (slot % NB) * 4 + (threadIdx.x >> 6);   // local node in graph
  if (ln >= nper) return;
  int n = g * nper + ln;
  int lane = threadIdx.x & 63;
  int cg = lane & 15;
  int cb = (lane >> 4) * 64 + cg * 4;              // this lane's 4 channels
  int deg = min(cnt[n], MAXDEG);
  // lane-parallel prefetch of edge ids + src ids (breaks the per-edge dep chain)
  int e_l = 0, s_l = 0;
  if (lane < deg) { e_l = csr[n * MAXDEG + lane]; s_l = srcv[e_l]; }
  float4 xd4 = *(const float4*)(xr + (size_t)n * 256 + cb);
  float4 at4 = *(const float4*)(att + cb);
  float4 w0 = *(const float4*)(We + 0 * 256 + cb);
  float4 w1 = *(const float4*)(We + 1 * 256 + cb);
  float4 w2 = *(const float4*)(We + 2 * 256 + cb);
  float4 w3 = *(const float4*)(We + 3 * 256 + cb);
  float4 w4_ = *(const float4*)(We + 4 * 256 + cb);
  float4 w5 = *(const float4*)(We + 5 * 256 + cb);
  float4 w6 = *(const float4*)(We + 6 * 256 + cb);
  float4 w7 = *(const float4*)(We + 7 * 256 + cb);
  float m = -INFINITY, l = 0.f;
  float ox = 0.f, oy = 0.f, oz = 0.f, ow = 0.f;
  for (int i0 = 0; i0 < deg; i0 += 4) {
    int c0 = deg - i0; if (c0 > 4) c0 = 4;         // wave-uniform
    float4 xs[4];
    float v[4];
#pragma unroll
    for (int j = 0; j < 4; ++j) {
      int idx = (j < c0) ? (i0 + j) : i0;          // clamp to a safe slot
      int e = __shfl(e_l, idx, 64);
      int s = __shfl(s_l, idx, 64);
      xs[j] = *(const float4*)(xl + (size_t)s * 256 + cb);   // independent, in flight
      float4 q0 = *(const float4*)(ea + (size_t)e * 8);
      float4 q1 = *(const float4*)(ea + (size_t)e * 8 + 4);
      float e0 = q0.x * w0.x + q0.y * w1.x + q0.z * w2.x + q0.w * w3.x
               + q1.x * w4_.x + q1.y * w5.x + q1.z * w6.x + q1.w * w7.x;
      float e1 = q0.x * w0.y + q0.y * w1.y + q0.z * w2.y + q0.w * w3.y
               + q1.x * w4_.y + q1.y * w5.y + q1.z * w6.y + q1.w * w7.y;
      float e2 = q0.x * w0.z + q0.y * w1.z + q0.z * w2.z + q0.w * w3.z
               + q1.x * w4_.z + q1.y * w5.z + q1.z * w6.z + q1.w * w7.z;
      float e3 = q0.x * w0.w + q0.y * w1.w + q0.z * w2.w + q0.w * w3.w
               + q1.x * w4_.w + q1.y * w5.w + q1.z * w6.w + q1.w * w7.w;
      float m0 = xs[j].x + xd4.x + e0; m0 = (m0 >= 0.f) ? m0 : 0.2f * m0;  // leaky 0.2
      float m1 = xs[j].y + xd4.y + e1; m1 = (m1 >= 0.f) ? m1 : 0.2f * m1;
      float m2 = xs[j].z + xd4.z + e2; m2 = (m2 >= 0.f) ? m2 : 0.2f * m2;
      float m3 = xs[j].w + xd4.w + e3; m3 = (m3 >= 0.f) ? m3 : 0.2f * m3;
      v[j] = at4.x * m0 + at4.y * m1 + at4.z * m2 + at4.w * m3;
    }
    // 4 independent 16-lane reductions, interleaved (ILP 4)
#pragma unroll
    for (int st = 1; st <= 8; st <<= 1) {
      v[0] += __shfl_xor(v[0], st, 64);
      v[1] += __shfl_xor(v[1], st, 64);
      v[2] += __shfl_xor(v[2], st, 64);
      v[3] += __shfl_xor(v[3], st, 64);
    }
    // batched online-softmax merge
    float vmax = v[0];
    if (c0 > 1) vmax = fmaxf(vmax, v[1]);
    if (c0 > 2) vmax = fmaxf(vmax, v[2]);
    if (c0 > 3) vmax = fmaxf(vmax, v[3]);
    float nm = fmaxf(m, vmax);
    float scale = __expf(m - nm);                  // exp(-inf - x) = 0 first chunk
    float p0 = __expf(v[0] - nm);
    float p1 = (c0 > 1) ? __expf(v[1] - nm) : 0.f;
    float p2 = (c0 > 2) ? __expf(v[2] - nm) : 0.f;
    float p3 = (c0 > 3) ? __expf(v[3] - nm) : 0.f;
    ox = ox * scale + p0 * xs[0].x + p1 * xs[1].x + p2 * xs[2].x + p3 * xs[3].x;
    oy = oy * scale + p0 * xs[0].y + p1 * xs[1].y + p2 * xs[2].y + p3 * xs[3].y;
    oz = oz * scale + p0 * xs[0].z + p1 * xs[1].z + p2 * xs[2].z + p3 * xs[3].z;
    ow = ow * scale + p0 * xs[0].w + p1 * xs[1].w + p2 * xs[2].w + p3 * xs[3].w;
    l = l * scale + p0 + p1 + p2 + p3;
    m = nm;
  }
  // per-head y = O/den, then 0.25 * head-sum  (deg==0 -> l=0 -> y=0, matches ref)
  float inv = 0.25f / fmaxf(l, 1e-16f);
  float r0 = ox * inv, r1 = oy * inv, r2 = oz * inv, r3 = ow * inv;
  r0 += __shfl_xor(r0, 16, 64); r0 += __shfl_xor(r0, 32, 64);
  r1 += __shfl_xor(r1, 16, 64); r1 += __shfl_xor(r1, 32, 64);
  r2 += __shfl_xor(r2, 16, 64); r2 += __shfl_xor(r2, 32, 64);
  r3 += __shfl_xor(r3, 16, 64); r3 += __shfl_xor(r3, 32, 64);
  float4 bi4 = *(const float4*)(bias + cg * 4);
  r0 = fmaxf(r0 + bi4.x, 0.f); r1 = fmaxf(r1 + bi4.y, 0.f);
  r2 = fmaxf(r2 + bi4.z, 0.f); r3 = fmaxf(r3 + bi4.w, 0.f);
  if (lane < 16) *(float4*)(out + (size_t)n * 64 + cg * 4) = float4{r0, r1, r2, r3};
  // topk score: s = tanh(h.w / ||w||)
  float4 pw4 = *(const float4*)(pwv + cg * 4);
  float dot = r0 * pw4.x + r1 * pw4.y + r2 * pw4.z + r3 * pw4.w;
  float wn = pw4.x * pw4.x + pw4.y * pw4.y + pw4.z * pw4.z + pw4.w * pw4.w;
  dot += __shfl_xor(dot, 1, 64); wn += __shfl_xor(wn, 1, 64);
  dot += __shfl_xor(dot, 2, 64); wn += __shfl_xor(wn, 2, 64);
  dot += __shfl_xor(dot, 4, 64); wn += __shfl_xor(wn, 4, 64);
  dot += __shfl_xor(dot, 8, 64); wn += __shfl_xor(wn, 8, 64);
  if (lane == 0) sc[n] = tanhf(dot / sqrtf(wn));
}

// stable descending sort per graph — u64 keys (ford(score)<<32 | ~idx), bitonic <=2048
__global__ __launch_bounds__(1024) void k_topk(const float* __restrict__ s, int n_per,
                                               int k, int npad,
                                               int* __restrict__ perm, int* __restrict__ new_id) {
  __shared__ u64 kv[2048];
  int b = blockIdx.x, tid = threadIdx.x;
  int base = b * n_per;
  for (int i = tid; i < n_per; i += 1024) new_id[base + i] = -1;
  for (int i = tid; i < npad; i += 1024) {
    u32 sk = (i < n_per) ? ford(s[base + i]) : 0u;   // pad key 0: below every real code
    kv[i] = ((u64)sk << 32) | (u32)(0xFFFFFFFFu - (u32)i);   // tie -> lower idx first
  }
  __syncthreads();
  for (int kk = 2; kk <= npad; kk <<= 1) {
    for (int j = kk >> 1; j > 0; j >>= 1) {
      for (int i = tid; i < npad; i += 1024) {
        int ixj = i ^ j;
        if (ixj > i) {
          u64 a = kv[i], c = kv[ixj];
          bool after = a < c;                        // descending order
          bool doswap = ((i & kk) == 0) ? after : !after;
          if (doswap) { kv[i] = c; kv[ixj] = a; }
        }
      }
      __syncthreads();
    }
  }
  for (int r = tid; r < k; r += 1024) {
    int old = (int)(0xFFFFFFFFu - (u32)(kv[r] & 0xFFFFFFFFu));
    perm[b * k + r] = base + old;
    new_id[base + old] = b * k + r;
  }
}

__global__ void k_gather(const float* __restrict__ hin, const float* __restrict__ s,
                         const int* __restrict__ perm, float* __restrict__ hout, int n64) {
  int t = blockIdx.x * blockDim.x + threadIdx.x;
  if (t >= n64) return;
  int i = t >> 6, c = t & 63;
  int g = perm[i];
  hout[t] = hin[(size_t)g * 64 + c] * s[g];
}

// remap edges AND build next layer's CSR (cnt pre-zeroed)
__global__ void k_remap_csr(int* __restrict__ src, int* __restrict__ dst,
                            int* __restrict__ em, const int* __restrict__ new_id,
                            int* __restrict__ cnt, int* __restrict__ csr) {
  int e = blockIdx.x * blockDim.x + threadIdx.x;
  if (e >= E_TOT) return;
  int ns = new_id[src[e]], nd = new_id[dst[e]];
  int m = em[e] && ns >= 0 && nd >= 0;
  src[e] = m ? ns : 0;
  dst[e] = m ? nd : 0;
  em[e] = m;
  if (m) {
    int pos = atomicAdd(&cnt[nd], 1);
    if (pos < MAXDEG) csr[nd * MAXDEG + pos] = e;
  }
}

// chunked parallel readout: grid (B, 16), 256 thr
__global__ void k_readout_part(const float* __restrict__ h, int k,
                               float* __restrict__ rsum, u32* __restrict__ rmaxI) {
  __shared__ float ps[256], pm[256];
  int b = blockIdx.x, ch = blockIdx.y, t = threadIdx.x;
  int c = t & 63, rg = t >> 6;
  int rpc = (k + 15) >> 4;
  int start = ch * rpc, end = min(k, start + rpc);
  const float* hb = h + (size_t)b * k * 64;
  float sum = 0.f, mx = -INFINITY;
  for (int i = start + rg; i < end; i += 4) {
    float v = hb[(size_t)i * 64 + c];
    sum += v;
    mx = fmaxf(mx, v);
  }
  ps[t] = sum; pm[t] = mx;
  __syncthreads();
  if (t < 64) {
    float s4 = ps[t] + ps[t + 64] + ps[t + 128] + ps[t + 192];
    float m4 = fmaxf(fmaxf(pm[t], pm[t + 64]), fmaxf(pm[t + 128], pm[t + 192]));
    atomicAdd(&rsum[b * 64 + t], s4);
    atomicMax(&rmaxI[b * 64 + t], ford(m4));
  }
}

__global__ void k_readout_fin(const float* __restrict__ rsum, const u32* __restrict__ rmaxI,
                              int k, float* __restrict__ r) {
  int b = blockIdx.x, c = threadIdx.x;   // 128 threads
  if (c < 64) r[b * 128 + c] += rsum[b * 64 + c] / (float)k;
  else        r[b * 128 + c] += ford_inv(rmaxI[b * 64 + (c - 64)]);
}

__global__ void k_mlp(const float* __restrict__ r,
                      const float* __restrict__ W1, const float* __restrict__ b1,
                      const float* __restrict__ W2, const float* __restrict__ b2,
                      const float* __restrict__ W3, const float* __restrict__ b3,
                      float* __restrict__ out) {
  __shared__ float v0[128], v1[64], v2[64], lgts[16];
  int b = blockIdx.x, t = threadIdx.x;   // 64 threads
  v0[t] = r[b * 128 + t];
  v0[64 + t] = r[b * 128 + 64 + t];
  __syncthreads();
  float a = b1[t];
  for (int i = 0; i < 128; ++i) a += v0[i] * W1[i * 64 + t];
  v1[t] = fmaxf(a, 0.f);
  __syncthreads();
  a = b2[t];
  for (int i = 0; i < 64; ++i) a += v1[i] * W2[i * 64 + t];
  v2[t] = fmaxf(a, 0.f);
  __syncthreads();
  if (t < 16) {
    a = b3[t];
    for (int i = 0; i < 64; ++i) a += v2[i] * W3[i * 16 + t];
    lgts[t] = a;
  }
  __syncthreads();
  if (t == 0) {
    float m = lgts[0];
    for (int j = 1; j < 16; ++j) m = fmaxf(m, lgts[j]);
    float ex[16], sum = 0.f;
    for (int j = 0; j < 16; ++j) { ex[j] = expf(lgts[j] - m); sum += ex[j]; }
    for (int j = 0; j < 16; ++j) out[b * 16 + j] = ex[j] / sum;
  }
}

extern "C" void kernel_launch(void* const* d_in, const int* in_sizes, int n_in,
                              void* d_out, int out_size, void* d_ws, size_t ws_size,
                              hipStream_t stream) {
  (void)in_sizes; (void)n_in; (void)out_size; (void)ws_size;
  const float* x  = (const float*)d_in[0];      // [NMAX, 32] f32
  const float* ea = (const float*)d_in[1];      // [E, 8]     f32
  const int*   ei = (const int*)d_in[2];        // [2, E]

  const float *gWl[3], *gbl[3], *gWr[3], *gbr[3], *gWe[3], *gatt[3], *gb[3], *pw[3];
  for (int l = 0; l < 3; ++l) {
    int p0 = 4 + 7 * l;
    gWl[l]  = (const float*)d_in[p0 + 0];
    gbl[l]  = (const float*)d_in[p0 + 1];
    gWr[l]  = (const float*)d_in[p0 + 2];
    gbr[l]  = (const float*)d_in[p0 + 3];
    gWe[l]  = (const float*)d_in[p0 + 4];
    gatt[l] = (const float*)d_in[p0 + 5];
    gb[l]   = (const float*)d_in[p0 + 6];
    pw[l]   = (const float*)d_in[25 + l];
  }
  const float* fc1W = (const float*)d_in[28];
  const float* fc1b = (const float*)d_in[29];
  const float* fc2W = (const float*)d_in[30];
  const float* fc2b = (const float*)d_in[31];
  const float* fc3W = (const float*)d_in[32];
  const float* fc3b = (const float*)d_in[33];

  // ---- workspace carve (~136.9 MB; fits per round-5 gate) ----
  char* w = (char*)d_ws;
  size_t off = 0;
  auto alloc = [&](size_t bytes) -> void* {
    void* p = w + off;
    off += (bytes + 255) & ~(size_t)255;
    return p;
  };
  float* hbuf = (float*)alloc((size_t)B_ * 1268 * 64 * 4); // pooled features (max K1)
  float* xl   = (float*)alloc((size_t)NMAX * 256 * 4);     // source transform [N,256]
  float* xr   = (float*)alloc((size_t)NMAX * 256 * 4);     // target transform [N,256]
  float* nacc = (float*)alloc((size_t)NMAX * 64 * 4);      // fused GAT output (pre-pool)
  int*   cnt  = (int*)alloc((size_t)NMAX * 4);             // CSR degree counters
  char*  rblk = (char*)alloc(32 * 128 * 4);                // [rsum 8KB][rmaxI 8KB], per layer
  float* rsum = (float*)rblk;
  u32*   rmaxI= (u32*)(rblk + 32 * 64 * 4);
  int*   csr  = (int*)alloc((size_t)NMAX * MAXDEG * 4);
  float* sbuf = (float*)alloc((size_t)NMAX * 4);
  float* rbuf = (float*)alloc(32 * 128 * 4);
  int* src    = (int*)alloc((size_t)E_TOT * 4);
  int* dst    = (int*)alloc((size_t)E_TOT * 4);
  int* em     = (int*)alloc((size_t)E_TOT * 4);
  int* new_id = (int*)alloc((size_t)NMAX * 4);
  int* perm   = (int*)alloc((size_t)32 * 1268 * 4);

  hipMemsetAsync(cnt, 0, (size_t)NMAX * 4, stream);
  k_edge_init_csr<<<CDIV(E_TOT, 256), 256, 0, stream>>>(ei, src, dst, em, cnt, csr);
  hipMemsetAsync(rbuf, 0, 32 * 128 * 4, stream);

  const int Ns[3]    = {50688, 40576, 32480};   // B*N0, B*K1, B*K2 (all %8==0)
  const int npers[3] = {1584, 1268, 1015};
  const int ks[3]    = {1268, 1015, 812};
  const int npads[3] = {2048, 2048, 1024};

  for (int l = 0; l < 3; ++l) {
    int N = Ns[l];
    int nper = npers[l];
    int NBg = CDIV(nper, 4);                 // gat blocks per graph
    const float* hin = (l == 0) ? x : hbuf;
    hipMemsetAsync(rblk, 0, 32 * 128 * 4, stream);
    if (l == 0)
      k_transform_t<32><<<N / 8, 256, 0, stream>>>(hin, gWl[l], gbl[l], gWr[l], gbr[l], xl, xr);
    else
      k_transform_t<64><<<N / 8, 256, 0, stream>>>(hin, gWl[l], gbl[l], gWr[l], gbr[l], xl, xr);
    k_gat_fused<<<32 * NBg, 256, 0, stream>>>(src, cnt, csr, ea, gWe[l], gatt[l],
                                              xl, xr, gb[l], pw[l], nacc, sbuf, nper, NBg);
    k_topk<<<32, 1024, 0, stream>>>(sbuf, nper, ks[l], npads[l], perm, new_id);
    k_gather<<<CDIV(B_ * ks[l] * 64, 256), 256, 0, stream>>>(nacc, sbuf, perm, hbuf,
                                                             B_ * ks[l] * 64);
    if (l < 2) {
      hipMemsetAsync(cnt, 0, (size_t)NMAX * 4, stream);
      k_remap_csr<<<CDIV(E_TOT, 256), 256, 0, stream>>>(src, dst, em, new_id, cnt, csr);
    }
    k_readout_part<<<dim3(32, 16), 256, 0, stream>>>(hbuf, ks[l], rsum, rmaxI);
    k_readout_fin<<<32, 128, 0, stream>>>(rsum, rmaxI, ks[l], rbuf);
  }
  k_mlp<<<32, 64, 0, stream>>>(rbuf, fc1W, fc1b, fc2W, fc2b, fc3W, fc3b, (float*)d_out);
}

// Round 13
// 595.356 us; speedup vs baseline: 1.0366x; 1.0327x over previous
//
#include <hip/hip_runtime.h>

typedef unsigned short u16;
typedef unsigned int u32;
typedef unsigned long long u64;

#define E_TOT 202752   // B*N0*DEG = 32*1584*4
#define NMAX  50688    // B*N0
#define HEADS 4
#define B_    32
#define MAXDEG 32      // Poisson(4) in-degree: P(>=32) ~ 1e-18/node — safe bucket

#define CDIV(a,b) (((a)+(b)-1)/(b))

// order-preserving float->uint map (monotonic); code 0 is below any real float's code
__device__ __forceinline__ u32 ford(float f) {
  u32 u = __float_as_uint(f);
  return (u & 0x80000000u) ? ~u : (u | 0x80000000u);
}
__device__ __forceinline__ float ford_inv(u32 u) {
  u32 b = (u & 0x80000000u) ? (u ^ 0x80000000u) : ~u;
  return __uint_as_float(b);
}

// edge arrays + CSR for layer 0 in one pass (cnt pre-zeroed)
__global__ void k_edge_init_csr(const int* __restrict__ ei, int* __restrict__ src,
                                int* __restrict__ dst, int* __restrict__ em,
                                int* __restrict__ cnt, int* __restrict__ csr) {
  int e = blockIdx.x * blockDim.x + threadIdx.x;
  if (e >= E_TOT) return;
  int s = ei[e], d = ei[E_TOT + e];
  src[e] = s;
  dst[e] = d;
  em[e] = 1;
  int pos = atomicAdd(&cnt[d], 1);
  if (pos < MAXDEG) csr[d * MAXDEG + pos] = e;
}

// ---------- node transform, 8 nodes/block, W columns reused in regs ----------
template <int FIN>
__global__ void k_transform_t(const float* __restrict__ hin,
                              const float* __restrict__ Wl, const float* __restrict__ bl,
                              const float* __restrict__ Wr, const float* __restrict__ br,
                              float* __restrict__ xl, float* __restrict__ xr) {
  __shared__ float xs[8][FIN];
  int n0 = blockIdx.x * 8, j = threadIdx.x;   // 256 threads
  for (int t = j; t < 8 * FIN; t += 256)
    xs[t >> (FIN == 32 ? 5 : 6)][t & (FIN - 1)] =
        hin[(size_t)(n0 + (t >> (FIN == 32 ? 5 : 6))) * FIN + (t & (FIN - 1))];
  __syncthreads();
  float al[8], ar[8];
  float blv = bl[j], brv = br[j];
#pragma unroll
  for (int t = 0; t < 8; ++t) { al[t] = blv; ar[t] = brv; }
  for (int i = 0; i < FIN; ++i) {
    float wl = Wl[i * 256 + j], wr = Wr[i * 256 + j];
#pragma unroll
    for (int t = 0; t < 8; ++t) {
      float xv = xs[t][i];
      al[t] += xv * wl;
      ar[t] += xv * wr;
    }
  }
#pragma unroll
  for (int t = 0; t < 8; ++t) {
    xl[(size_t)(n0 + t) * 256 + j] = al[t];
    xr[(size_t)(n0 + t) * 256 + j] = ar[t];
  }
}

// ---------- fused GATv2: 4 nodes per wave (sequential, cross-node prefetch) ----------
// grid = 32 * NB, NB = ceil(nper/16); block = 4 waves x 4 nodes
// lane = (head h = lane>>4, chan-group cg = lane&15)
__global__ __launch_bounds__(256, 4)
void k_gat_fused(const int* __restrict__ srcv, const int* __restrict__ cnt,
                 const int* __restrict__ csr, const float* __restrict__ ea,
                 const float* __restrict__ We, const float* __restrict__ att,
                 const float* __restrict__ xl, const float* __restrict__ xr,
                 const float* __restrict__ bias, const float* __restrict__ pwv,
                 float* __restrict__ out, float* __restrict__ sc,
                 int nper, int NB) {
  int b = blockIdx.x;
  int xcd = b & 7, slot = b >> 3;
  int g = xcd + 8 * (slot / NB);
  int ln0 = (slot % NB) * 16 + (threadIdx.x >> 6) * 4;   // first of this wave's 4 nodes
  int lane = threadIdx.x & 63;
  int cg = lane & 15;
  int cb = (lane >> 4) * 64 + cg * 4;                    // this lane's 4 channels
  int nbase = g * nper;
  // per-layer constants, hoisted once per wave
  float4 at4 = *(const float4*)(att + cb);
  float4 w0 = *(const float4*)(We + 0 * 256 + cb);
  float4 w1 = *(const float4*)(We + 1 * 256 + cb);
  float4 w2 = *(const float4*)(We + 2 * 256 + cb);
  float4 w3 = *(const float4*)(We + 3 * 256 + cb);
  float4 w4_ = *(const float4*)(We + 4 * 256 + cb);
  float4 w5 = *(const float4*)(We + 5 * 256 + cb);
  float4 w6 = *(const float4*)(We + 6 * 256 + cb);
  float4 w7 = *(const float4*)(We + 7 * 256 + cb);
  float4 bi4 = *(const float4*)(bias + cg * 4);
  float4 pw4 = *(const float4*)(pwv + cg * 4);
  float wn = pw4.x * pw4.x + pw4.y * pw4.y + pw4.z * pw4.z + pw4.w * pw4.w;
  wn += __shfl_xor(wn, 1, 64); wn += __shfl_xor(wn, 2, 64);
  wn += __shfl_xor(wn, 4, 64); wn += __shfl_xor(wn, 8, 64);
  float isq = 1.f / sqrtf(wn);                           // once per wave, not per node

  // prefetch node 0 state
  int ln = ln0;
  bool valid = ln < nper;
  int n = nbase + ln;
  int deg = 0, e_l = 0, s_l = 0;
  float4 xd4 = float4{0.f, 0.f, 0.f, 0.f};
  if (valid) {
    deg = min(cnt[n], MAXDEG);
    if (lane < deg) { e_l = csr[n * MAXDEG + lane]; s_l = srcv[e_l]; }
    xd4 = *(const float4*)(xr + (size_t)n * 256 + cb);
  }

  for (int i = 0; i < 4; ++i) {
    // capture current node, then prefetch next (loads fly during current compute)
    bool cval = valid; int curn = n, cdeg = deg, ce = e_l, cs = s_l;
    float4 cxd = xd4;
    if (i < 3) {
      ln = ln0 + i + 1;
      valid = ln < nper;
      n = nbase + ln;
      deg = 0; e_l = 0; s_l = 0;
      xd4 = float4{0.f, 0.f, 0.f, 0.f};
      if (valid) {
        deg = min(cnt[n], MAXDEG);
        if (lane < deg) { e_l = csr[n * MAXDEG + lane]; s_l = srcv[e_l]; }
        xd4 = *(const float4*)(xr + (size_t)n * 256 + cb);
      }
    }
    if (!cval) continue;                                 // wave-uniform

    float m = -INFINITY, l = 0.f;
    float ox = 0.f, oy = 0.f, oz = 0.f, ow = 0.f;
    for (int i0 = 0; i0 < cdeg; i0 += 4) {
      int c0 = cdeg - i0; if (c0 > 4) c0 = 4;            // wave-uniform
      float4 xs[4], a0[4], a1[4];
#pragma unroll
      for (int j = 0; j < 4; ++j) {
        int idx = (j < c0) ? (i0 + j) : i0;              // clamp to a safe slot
        int e = __shfl(ce, idx, 64);
        int s = __shfl(cs, idx, 64);
        xs[j] = *(const float4*)(xl + (size_t)s * 256 + cb);   // independent, in flight
        a0[j] = *(const float4*)(ea + (size_t)e * 8);
        a1[j] = *(const float4*)(ea + (size_t)e * 8 + 4);
      }
#pragma unroll
      for (int j = 0; j < 4; ++j) {
        if (j < c0) {
          float e0 = a0[j].x * w0.x + a0[j].y * w1.x + a0[j].z * w2.x + a0[j].w * w3.x
                   + a1[j].x * w4_.x + a1[j].y * w5.x + a1[j].z * w6.x + a1[j].w * w7.x;
          float e1 = a0[j].x * w0.y + a0[j].y * w1.y + a0[j].z * w2.y + a0[j].w * w3.y
                   + a1[j].x * w4_.y + a1[j].y * w5.y + a1[j].z * w6.y + a1[j].w * w7.y;
          float e2 = a0[j].x * w0.z + a0[j].y * w1.z + a0[j].z * w2.z + a0[j].w * w3.z
                   + a1[j].x * w4_.z + a1[j].y * w5.z + a1[j].z * w6.z + a1[j].w * w7.z;
          float e3 = a0[j].x * w0.w + a0[j].y * w1.w + a0[j].z * w2.w + a0[j].w * w3.w
                   + a1[j].x * w4_.w + a1[j].y * w5.w + a1[j].z * w6.w + a1[j].w * w7.w;
          float m0 = xs[j].x + cxd.x + e0; m0 = (m0 >= 0.f) ? m0 : 0.2f * m0;  // leaky 0.2
          float m1 = xs[j].y + cxd.y + e1; m1 = (m1 >= 0.f) ? m1 : 0.2f * m1;
          float m2 = xs[j].z + cxd.z + e2; m2 = (m2 >= 0.f) ? m2 : 0.2f * m2;
          float m3 = xs[j].w + cxd.w + e3; m3 = (m3 >= 0.f) ? m3 : 0.2f * m3;
          float v = at4.x * m0 + at4.y * m1 + at4.z * m2 + at4.w * m3;
          v += __shfl_xor(v, 1, 64);
          v += __shfl_xor(v, 2, 64);
          v += __shfl_xor(v, 4, 64);
          v += __shfl_xor(v, 8, 64);     // all 16 head-lanes hold the head logit
          float nm = fmaxf(m, v);
          float scale = __expf(m - nm);  // exp(-inf - x) = 0 handles first edge
          float p = __expf(v - nm);
          ox = ox * scale + p * xs[j].x;
          oy = oy * scale + p * xs[j].y;
          oz = oz * scale + p * xs[j].z;
          ow = ow * scale + p * xs[j].w;
          l = l * scale + p;
          m = nm;
        }
      }
    }
    // per-head y = O/den, then 0.25 * head-sum  (deg==0 -> l=0 -> y=0, matches ref)
    float inv = 0.25f / fmaxf(l, 1e-16f);
    float r0 = ox * inv, r1 = oy * inv, r2 = oz * inv, r3 = ow * inv;
    r0 += __shfl_xor(r0, 16, 64); r0 += __shfl_xor(r0, 32, 64);
    r1 += __shfl_xor(r1, 16, 64); r1 += __shfl_xor(r1, 32, 64);
    r2 += __shfl_xor(r2, 16, 64); r2 += __shfl_xor(r2, 32, 64);
    r3 += __shfl_xor(r3, 16, 64); r3 += __shfl_xor(r3, 32, 64);
    r0 = fmaxf(r0 + bi4.x, 0.f); r1 = fmaxf(r1 + bi4.y, 0.f);
    r2 = fmaxf(r2 + bi4.z, 0.f); r3 = fmaxf(r3 + bi4.w, 0.f);
    if (lane < 16) *(float4*)(out + (size_t)curn * 64 + cg * 4) = float4{r0, r1, r2, r3};
    // topk score: s = tanh(h.w / ||w||)
    float dot = r0 * pw4.x + r1 * pw4.y + r2 * pw4.z + r3 * pw4.w;
    dot += __shfl_xor(dot, 1, 64);
    dot += __shfl_xor(dot, 2, 64);
    dot += __shfl_xor(dot, 4, 64);
    dot += __shfl_xor(dot, 8, 64);
    if (lane == 0) sc[curn] = tanhf(dot * isq);
  }
}

// stable descending sort per graph — u64 keys (ford(score)<<32 | ~idx), bitonic <=2048
__global__ __launch_bounds__(1024) void k_topk(const float* __restrict__ s, int n_per,
                                               int k, int npad,
                                               int* __restrict__ perm, int* __restrict__ new_id) {
  __shared__ u64 kv[2048];
  int b = blockIdx.x, tid = threadIdx.x;
  int base = b * n_per;
  for (int i = tid; i < n_per; i += 1024) new_id[base + i] = -1;
  for (int i = tid; i < npad; i += 1024) {
    u32 sk = (i < n_per) ? ford(s[base + i]) : 0u;   // pad key 0: below every real code
    kv[i] = ((u64)sk << 32) | (u32)(0xFFFFFFFFu - (u32)i);   // tie -> lower idx first
  }
  __syncthreads();
  for (int kk = 2; kk <= npad; kk <<= 1) {
    for (int j = kk >> 1; j > 0; j >>= 1) {
      for (int i = tid; i < npad; i += 1024) {
        int ixj = i ^ j;
        if (ixj > i) {
          u64 a = kv[i], c = kv[ixj];
          bool after = a < c;                        // descending order
          bool doswap = ((i & kk) == 0) ? after : !after;
          if (doswap) { kv[i] = c; kv[ixj] = a; }
        }
      }
      __syncthreads();
    }
  }
  for (int r = tid; r < k; r += 1024) {
    int old = (int)(0xFFFFFFFFu - (u32)(kv[r] & 0xFFFFFFFFu));
    perm[b * k + r] = base + old;
    new_id[base + old] = b * k + r;
  }
}

__global__ void k_gather(const float* __restrict__ hin, const float* __restrict__ s,
                         const int* __restrict__ perm, float* __restrict__ hout, int n64) {
  int t = blockIdx.x * blockDim.x + threadIdx.x;
  if (t >= n64) return;
  int i = t >> 6, c = t & 63;
  int g = perm[i];
  hout[t] = hin[(size_t)g * 64 + c] * s[g];
}

// remap edges AND build next layer's CSR (cnt pre-zeroed)
__global__ void k_remap_csr(int* __restrict__ src, int* __restrict__ dst,
                            int* __restrict__ em, const int* __restrict__ new_id,
                            int* __restrict__ cnt, int* __restrict__ csr) {
  int e = blockIdx.x * blockDim.x + threadIdx.x;
  if (e >= E_TOT) return;
  int ns = new_id[src[e]], nd = new_id[dst[e]];
  int m = em[e] && ns >= 0 && nd >= 0;
  src[e] = m ? ns : 0;
  dst[e] = m ? nd : 0;
  em[e] = m;
  if (m) {
    int pos = atomicAdd(&cnt[nd], 1);
    if (pos < MAXDEG) csr[nd * MAXDEG + pos] = e;
  }
}

// chunked parallel readout: grid (B, 16), 256 thr
__global__ void k_readout_part(const float* __restrict__ h, int k,
                               float* __restrict__ rsum, u32* __restrict__ rmaxI) {
  __shared__ float ps[256], pm[256];
  int b = blockIdx.x, ch = blockIdx.y, t = threadIdx.x;
  int c = t & 63, rg = t >> 6;
  int rpc = (k + 15) >> 4;
  int start = ch * rpc, end = min(k, start + rpc);
  const float* hb = h + (size_t)b * k * 64;
  float sum = 0.f, mx = -INFINITY;
  for (int i = start + rg; i < end; i += 4) {
    float v = hb[(size_t)i * 64 + c];
    sum += v;
    mx = fmaxf(mx, v);
  }
  ps[t] = sum; pm[t] = mx;
  __syncthreads();
  if (t < 64) {
    float s4 = ps[t] + ps[t + 64] + ps[t + 128] + ps[t + 192];
    float m4 = fmaxf(fmaxf(pm[t], pm[t + 64]), fmaxf(pm[t + 128], pm[t + 192]));
    atomicAdd(&rsum[b * 64 + t], s4);
    atomicMax(&rmaxI[b * 64 + t], ford(m4));
  }
}

__global__ void k_readout_fin(const float* __restrict__ rsum, const u32* __restrict__ rmaxI,
                              int k, float* __restrict__ r) {
  int b = blockIdx.x, c = threadIdx.x;   // 128 threads
  if (c < 64) r[b * 128 + c] += rsum[b * 64 + c] / (float)k;
  else        r[b * 128 + c] += ford_inv(rmaxI[b * 64 + (c - 64)]);
}

__global__ void k_mlp(const float* __restrict__ r,
                      const float* __restrict__ W1, const float* __restrict__ b1,
                      const float* __restrict__ W2, const float* __restrict__ b2,
                      const float* __restrict__ W3, const float* __restrict__ b3,
                      float* __restrict__ out) {
  __shared__ float v0[128], v1[64], v2[64], lgts[16];
  int b = blockIdx.x, t = threadIdx.x;   // 64 threads
  v0[t] = r[b * 128 + t];
  v0[64 + t] = r[b * 128 + 64 + t];
  __syncthreads();
  float a = b1[t];
  for (int i = 0; i < 128; ++i) a += v0[i] * W1[i * 64 + t];
  v1[t] = fmaxf(a, 0.f);
  __syncthreads();
  a = b2[t];
  for (int i = 0; i < 64; ++i) a += v1[i] * W2[i * 64 + t];
  v2[t] = fmaxf(a, 0.f);
  __syncthreads();
  if (t < 16) {
    a = b3[t];
    for (int i = 0; i < 64; ++i) a += v2[i] * W3[i * 16 + t];
    lgts[t] = a;
  }
  __syncthreads();
  if (t == 0) {
    float m = lgts[0];
    for (int j = 1; j < 16; ++j) m = fmaxf(m, lgts[j]);
    float ex[16], sum = 0.f;
    for (int j = 0; j < 16; ++j) { ex[j] = expf(lgts[j] - m); sum += ex[j]; }
    for (int j = 0; j < 16; ++j) out[b * 16 + j] = ex[j] / sum;
  }
}

extern "C" void kernel_launch(void* const* d_in, const int* in_sizes, int n_in,
                              void* d_out, int out_size, void* d_ws, size_t ws_size,
                              hipStream_t stream) {
  (void)in_sizes; (void)n_in; (void)out_size; (void)ws_size;
  const float* x  = (const float*)d_in[0];      // [NMAX, 32] f32
  const float* ea = (const float*)d_in[1];      // [E, 8]     f32
  const int*   ei = (const int*)d_in[2];        // [2, E]

  const float *gWl[3], *gbl[3], *gWr[3], *gbr[3], *gWe[3], *gatt[3], *gb[3], *pw[3];
  for (int l = 0; l < 3; ++l) {
    int p0 = 4 + 7 * l;
    gWl[l]  = (const float*)d_in[p0 + 0];
    gbl[l]  = (const float*)d_in[p0 + 1];
    gWr[l]  = (const float*)d_in[p0 + 2];
    gbr[l]  = (const float*)d_in[p0 + 3];
    gWe[l]  = (const float*)d_in[p0 + 4];
    gatt[l] = (const float*)d_in[p0 + 5];
    gb[l]   = (const float*)d_in[p0 + 6];
    pw[l]   = (const float*)d_in[25 + l];
  }
  const float* fc1W = (const float*)d_in[28];
  const float* fc1b = (const float*)d_in[29];
  const float* fc2W = (const float*)d_in[30];
  const float* fc2b = (const float*)d_in[31];
  const float* fc3W = (const float*)d_in[32];
  const float* fc3b = (const float*)d_in[33];

  // ---- workspace carve (~136.9 MB; fits per round-5 gate) ----
  char* w = (char*)d_ws;
  size_t off = 0;
  auto alloc = [&](size_t bytes) -> void* {
    void* p = w + off;
    off += (bytes + 255) & ~(size_t)255;
    return p;
  };
  float* hbuf = (float*)alloc((size_t)B_ * 1268 * 64 * 4); // pooled features (max K1)
  float* xl   = (float*)alloc((size_t)NMAX * 256 * 4);     // source transform [N,256]
  float* xr   = (float*)alloc((size_t)NMAX * 256 * 4);     // target transform [N,256]
  float* nacc = (float*)alloc((size_t)NMAX * 64 * 4);      // fused GAT output (pre-pool)
  int*   cnt  = (int*)alloc((size_t)NMAX * 4);             // CSR degree counters
  char*  rblk = (char*)alloc(32 * 128 * 4);                // [rsum 8KB][rmaxI 8KB], per layer
  float* rsum = (float*)rblk;
  u32*   rmaxI= (u32*)(rblk + 32 * 64 * 4);
  int*   csr  = (int*)alloc((size_t)NMAX * MAXDEG * 4);
  float* sbuf = (float*)alloc((size_t)NMAX * 4);
  float* rbuf = (float*)alloc(32 * 128 * 4);
  int* src    = (int*)alloc((size_t)E_TOT * 4);
  int* dst    = (int*)alloc((size_t)E_TOT * 4);
  int* em     = (int*)alloc((size_t)E_TOT * 4);
  int* new_id = (int*)alloc((size_t)NMAX * 4);
  int* perm   = (int*)alloc((size_t)32 * 1268 * 4);

  hipMemsetAsync(cnt, 0, (size_t)NMAX * 4, stream);
  k_edge_init_csr<<<CDIV(E_TOT, 256), 256, 0, stream>>>(ei, src, dst, em, cnt, csr);
  hipMemsetAsync(rbuf, 0, 32 * 128 * 4, stream);

  const int Ns[3]    = {50688, 40576, 32480};   // B*N0, B*K1, B*K2 (all %8==0)
  const int npers[3] = {1584, 1268, 1015};
  const int ks[3]    = {1268, 1015, 812};
  const int npads[3] = {2048, 2048, 1024};

  for (int l = 0; l < 3; ++l) {
    int N = Ns[l];
    int nper = npers[l];
    int NBg = CDIV(nper, 16);                // gat blocks per graph (16 nodes/block)
    const float* hin = (l == 0) ? x : hbuf;
    hipMemsetAsync(rblk, 0, 32 * 128 * 4, stream);
    if (l == 0)
      k_transform_t<32><<<N / 8, 256, 0, stream>>>(hin, gWl[l], gbl[l], gWr[l], gbr[l], xl, xr);
    else
      k_transform_t<64><<<N / 8, 256, 0, stream>>>(hin, gWl[l], gbl[l], gWr[l], gbr[l], xl, xr);
    k_gat_fused<<<32 * NBg, 256, 0, stream>>>(src, cnt, csr, ea, gWe[l], gatt[l],
                                              xl, xr, gb[l], pw[l], nacc, sbuf, nper, NBg);
    k_topk<<<32, 1024, 0, stream>>>(sbuf, nper, ks[l], npads[l], perm, new_id);
    k_gather<<<CDIV(B_ * ks[l] * 64, 256), 256, 0, stream>>>(nacc, sbuf, perm, hbuf,
                                                             B_ * ks[l] * 64);
    if (l < 2) {
      hipMemsetAsync(cnt, 0, (size_t)NMAX * 4, stream);
      k_remap_csr<<<CDIV(E_TOT, 256), 256, 0, stream>>>(src, dst, em, new_id, cnt, csr);
    }
    k_readout_part<<<dim3(32, 16), 256, 0, stream>>>(hbuf, ks[l], rsum, rmaxI);
    k_readout_fin<<<32, 128, 0, stream>>>(rsum, rmaxI, ks[l], rbuf);
  }
  k_mlp<<<32, 64, 0, stream>>>(rbuf, fc1W, fc1b, fc2W, fc2b, fc3W, fc3b, (float*)d_out);
}

// Round 14
// 550.180 us; speedup vs baseline: 1.1217x; 1.0821x over previous
//
#include <hip/hip_runtime.h>

typedef unsigned short u16;
typedef unsigned int u32;
typedef unsigned long long u64;

#define E_TOT 202752   // B*N0*DEG = 32*1584*4
#define NMAX  50688    // B*N0
#define HEADS 4
#define B_    32
#define MAXDEG 32      // Poisson(4) in-degree: P(>=32) ~ 1e-18/node — safe bucket

#define CDIV(a,b) (((a)+(b)-1)/(b))

// order-preserving float->uint map (monotonic); code 0 is below any real float's code
__device__ __forceinline__ u32 ford(float f) {
  u32 u = __float_as_uint(f);
  return (u & 0x80000000u) ? ~u : (u | 0x80000000u);
}
__device__ __forceinline__ float ford_inv(u32 u) {
  u32 b = (u & 0x80000000u) ? (u ^ 0x80000000u) : ~u;
  return __uint_as_float(b);
}

// edge arrays + CSR for layer 0 in one pass (cnt pre-zeroed)
__global__ void k_edge_init_csr(const int* __restrict__ ei, int* __restrict__ src,
                                int* __restrict__ dst, int* __restrict__ em,
                                int* __restrict__ cnt, int* __restrict__ csr) {
  int e = blockIdx.x * blockDim.x + threadIdx.x;
  if (e >= E_TOT) return;
  int s = ei[e], d = ei[E_TOT + e];
  src[e] = s;
  dst[e] = d;
  em[e] = 1;
  int pos = atomicAdd(&cnt[d], 1);
  if (pos < MAXDEG) csr[d * MAXDEG + pos] = e;
}

// ---------- node transform, 16 nodes/block, transposed-LDS x, b128 broadcast reads ----
// xs[FIN][20]: pad 16+4 keeps every row 80B (16B-aligned for float4) and spreads banks
template <int FIN>
__global__ void k_transform_t(const float* __restrict__ hin,
                              const float* __restrict__ Wl, const float* __restrict__ bl,
                              const float* __restrict__ Wr, const float* __restrict__ br,
                              float* __restrict__ xl, float* __restrict__ xr) {
  __shared__ float xs[FIN][20];
  int n0 = blockIdx.x * 16, j = threadIdx.x;   // 256 threads
  for (int t = j; t < 16 * FIN; t += 256) {
    int nd = t >> (FIN == 32 ? 5 : 6), f = t & (FIN - 1);
    xs[f][nd] = hin[(size_t)(n0 + nd) * FIN + f];
  }
  __syncthreads();
  float al[16], ar[16];
  float blv = bl[j], brv = br[j];
#pragma unroll
  for (int t = 0; t < 16; ++t) { al[t] = blv; ar[t] = brv; }
  for (int i = 0; i < FIN; ++i) {
    float wl = Wl[i * 256 + j], wr = Wr[i * 256 + j];
    float4 x0 = *(const float4*)&xs[i][0];     // broadcast b128 reads
    float4 x1 = *(const float4*)&xs[i][4];
    float4 x2 = *(const float4*)&xs[i][8];
    float4 x3 = *(const float4*)&xs[i][12];
    al[0]  += x0.x * wl; ar[0]  += x0.x * wr;
    al[1]  += x0.y * wl; ar[1]  += x0.y * wr;
    al[2]  += x0.z * wl; ar[2]  += x0.z * wr;
    al[3]  += x0.w * wl; ar[3]  += x0.w * wr;
    al[4]  += x1.x * wl; ar[4]  += x1.x * wr;
    al[5]  += x1.y * wl; ar[5]  += x1.y * wr;
    al[6]  += x1.z * wl; ar[6]  += x1.z * wr;
    al[7]  += x1.w * wl; ar[7]  += x1.w * wr;
    al[8]  += x2.x * wl; ar[8]  += x2.x * wr;
    al[9]  += x2.y * wl; ar[9]  += x2.y * wr;
    al[10] += x2.z * wl; ar[10] += x2.z * wr;
    al[11] += x2.w * wl; ar[11] += x2.w * wr;
    al[12] += x3.x * wl; ar[12] += x3.x * wr;
    al[13] += x3.y * wl; ar[13] += x3.y * wr;
    al[14] += x3.z * wl; ar[14] += x3.z * wr;
    al[15] += x3.w * wl; ar[15] += x3.w * wr;
  }
#pragma unroll
  for (int t = 0; t < 16; ++t) {
    xl[(size_t)(n0 + t) * 256 + j] = al[t];
    xr[(size_t)(n0 + t) * 256 + j] = ar[t];
  }
}

// ---------- fused GATv2 per dst node (round-10 form — empirical optimum) ----------
// grid = N/4; 4 waves/block, 1 node/wave; lane = (head h = lane>>4, chan-group cg)
__global__ void k_gat_fused(const int* __restrict__ srcv, const int* __restrict__ cnt,
                            const int* __restrict__ csr, const float* __restrict__ ea,
                            const float* __restrict__ We, const float* __restrict__ att,
                            const float* __restrict__ xl, const float* __restrict__ xr,
                            const float* __restrict__ bias, const float* __restrict__ pwv,
                            float* __restrict__ out, float* __restrict__ sc, int N) {
  int n = blockIdx.x * 4 + (threadIdx.x >> 6);
  int lane = threadIdx.x & 63;
  int cg = lane & 15;
  int cb = (lane >> 4) * 64 + cg * 4;              // this lane's 4 channels
  if (n >= N) return;
  int deg = min(cnt[n], MAXDEG);
  // lane-parallel prefetch of edge ids + src ids (breaks the per-edge dep chain)
  int e_l = 0, s_l = 0;
  if (lane < deg) { e_l = csr[n * MAXDEG + lane]; s_l = srcv[e_l]; }
  float4 xd4 = *(const float4*)(xr + (size_t)n * 256 + cb);
  float4 at4 = *(const float4*)(att + cb);
  float4 w0 = *(const float4*)(We + 0 * 256 + cb);
  float4 w1 = *(const float4*)(We + 1 * 256 + cb);
  float4 w2 = *(const float4*)(We + 2 * 256 + cb);
  float4 w3 = *(const float4*)(We + 3 * 256 + cb);
  float4 w4_ = *(const float4*)(We + 4 * 256 + cb);
  float4 w5 = *(const float4*)(We + 5 * 256 + cb);
  float4 w6 = *(const float4*)(We + 6 * 256 + cb);
  float4 w7 = *(const float4*)(We + 7 * 256 + cb);
  float4 pw4 = *(const float4*)(pwv + cg * 4);
  float wn = pw4.x * pw4.x + pw4.y * pw4.y + pw4.z * pw4.z + pw4.w * pw4.w;
  wn += __shfl_xor(wn, 1, 64); wn += __shfl_xor(wn, 2, 64);
  wn += __shfl_xor(wn, 4, 64); wn += __shfl_xor(wn, 8, 64);
  float isq = 1.f / sqrtf(wn);
  float m = -INFINITY, l = 0.f;
  float ox = 0.f, oy = 0.f, oz = 0.f, ow = 0.f;
  for (int i0 = 0; i0 < deg; i0 += 4) {
    int c0 = deg - i0; if (c0 > 4) c0 = 4;         // wave-uniform
    float4 xs[4], a0[4], a1[4];
#pragma unroll
    for (int j = 0; j < 4; ++j) {
      int idx = (j < c0) ? (i0 + j) : i0;          // clamp to a safe slot
      int e = __shfl(e_l, idx, 64);
      int s = __shfl(s_l, idx, 64);
      xs[j] = *(const float4*)(xl + (size_t)s * 256 + cb);   // independent, in flight
      a0[j] = *(const float4*)(ea + (size_t)e * 8);
      a1[j] = *(const float4*)(ea + (size_t)e * 8 + 4);
    }
#pragma unroll
    for (int j = 0; j < 4; ++j) {
      if (j < c0) {
        float e0 = a0[j].x * w0.x + a0[j].y * w1.x + a0[j].z * w2.x + a0[j].w * w3.x
                 + a1[j].x * w4_.x + a1[j].y * w5.x + a1[j].z * w6.x + a1[j].w * w7.x;
        float e1 = a0[j].x * w0.y + a0[j].y * w1.y + a0[j].z * w2.y + a0[j].w * w3.y
                 + a1[j].x * w4_.y + a1[j].y * w5.y + a1[j].z * w6.y + a1[j].w * w7.y;
        float e2 = a0[j].x * w0.z + a0[j].y * w1.z + a0[j].z * w2.z + a0[j].w * w3.z
                 + a1[j].x * w4_.z + a1[j].y * w5.z + a1[j].z * w6.z + a1[j].w * w7.z;
        float e3 = a0[j].x * w0.w + a0[j].y * w1.w + a0[j].z * w2.w + a0[j].w * w3.w
                 + a1[j].x * w4_.w + a1[j].y * w5.w + a1[j].z * w6.w + a1[j].w * w7.w;
        float m0 = xs[j].x + xd4.x + e0; m0 = (m0 >= 0.f) ? m0 : 0.2f * m0;  // leaky 0.2
        float m1 = xs[j].y + xd4.y + e1; m1 = (m1 >= 0.f) ? m1 : 0.2f * m1;
        float m2 = xs[j].z + xd4.z + e2; m2 = (m2 >= 0.f) ? m2 : 0.2f * m2;
        float m3 = xs[j].w + xd4.w + e3; m3 = (m3 >= 0.f) ? m3 : 0.2f * m3;
        float v = at4.x * m0 + at4.y * m1 + at4.z * m2 + at4.w * m3;
        v += __shfl_xor(v, 1, 64);
        v += __shfl_xor(v, 2, 64);
        v += __shfl_xor(v, 4, 64);
        v += __shfl_xor(v, 8, 64);     // all 16 head-lanes hold the head logit
        float nm = fmaxf(m, v);
        float scale = __expf(m - nm);  // exp(-inf - x) = 0 handles first edge
        float p = __expf(v - nm);
        ox = ox * scale + p * xs[j].x;
        oy = oy * scale + p * xs[j].y;
        oz = oz * scale + p * xs[j].z;
        ow = ow * scale + p * xs[j].w;
        l = l * scale + p;
        m = nm;
      }
    }
  }
  // per-head y = O/den, then 0.25 * head-sum  (deg==0 -> l=0 -> y=0, matches ref)
  float inv = 0.25f / fmaxf(l, 1e-16f);
  float r0 = ox * inv, r1 = oy * inv, r2 = oz * inv, r3 = ow * inv;
  r0 += __shfl_xor(r0, 16, 64); r0 += __shfl_xor(r0, 32, 64);
  r1 += __shfl_xor(r1, 16, 64); r1 += __shfl_xor(r1, 32, 64);
  r2 += __shfl_xor(r2, 16, 64); r2 += __shfl_xor(r2, 32, 64);
  r3 += __shfl_xor(r3, 16, 64); r3 += __shfl_xor(r3, 32, 64);
  float4 bi4 = *(const float4*)(bias + cg * 4);
  r0 = fmaxf(r0 + bi4.x, 0.f); r1 = fmaxf(r1 + bi4.y, 0.f);
  r2 = fmaxf(r2 + bi4.z, 0.f); r3 = fmaxf(r3 + bi4.w, 0.f);
  if (lane < 16) *(float4*)(out + (size_t)n * 64 + cg * 4) = float4{r0, r1, r2, r3};
  // topk score: s = tanh(h.w / ||w||)
  float dot = r0 * pw4.x + r1 * pw4.y + r2 * pw4.z + r3 * pw4.w;
  dot += __shfl_xor(dot, 1, 64);
  dot += __shfl_xor(dot, 2, 64);
  dot += __shfl_xor(dot, 4, 64);
  dot += __shfl_xor(dot, 8, 64);
  if (lane == 0) sc[n] = tanhf(dot * isq);
}

// stable descending sort per graph — u64 keys (ford(score)<<32 | ~idx), bitonic <=2048
__global__ __launch_bounds__(1024) void k_topk(const float* __restrict__ s, int n_per,
                                               int k, int npad,
                                               int* __restrict__ perm, int* __restrict__ new_id) {
  __shared__ u64 kv[2048];
  int b = blockIdx.x, tid = threadIdx.x;
  int base = b * n_per;
  for (int i = tid; i < n_per; i += 1024) new_id[base + i] = -1;
  for (int i = tid; i < npad; i += 1024) {
    u32 sk = (i < n_per) ? ford(s[base + i]) : 0u;   // pad key 0: below every real code
    kv[i] = ((u64)sk << 32) | (u32)(0xFFFFFFFFu - (u32)i);   // tie -> lower idx first
  }
  __syncthreads();
  for (int kk = 2; kk <= npad; kk <<= 1) {
    for (int j = kk >> 1; j > 0; j >>= 1) {
      for (int i = tid; i < npad; i += 1024) {
        int ixj = i ^ j;
        if (ixj > i) {
          u64 a = kv[i], c = kv[ixj];
          bool after = a < c;                        // descending order
          bool doswap = ((i & kk) == 0) ? after : !after;
          if (doswap) { kv[i] = c; kv[ixj] = a; }
        }
      }
      __syncthreads();
    }
  }
  for (int r = tid; r < k; r += 1024) {
    int old = (int)(0xFFFFFFFFu - (u32)(kv[r] & 0xFFFFFFFFu));
    perm[b * k + r] = base + old;
    new_id[base + old] = b * k + r;
  }
}

// fused gather + readout partials: grid (B, ceil(k/4)), 256 thr (4 nodes/block)
__global__ void k_gather_ro(const float* __restrict__ hin, const float* __restrict__ s,
                            const int* __restrict__ perm, float* __restrict__ hout,
                            int k, float* __restrict__ rsum, u32* __restrict__ rmaxI) {
  __shared__ float ps[256], pm[256];
  int b = blockIdx.x, t = threadIdx.x;
  int i = blockIdx.y * 4 + (t >> 6);            // local kept-node index
  int c = t & 63;
  bool valid = i < k;
  float v = 0.f;
  if (valid) {
    int g = perm[b * k + i];
    v = hin[(size_t)g * 64 + c] * s[g];
    hout[((size_t)b * k + i) * 64 + c] = v;
  }
  ps[t] = valid ? v : 0.f;
  pm[t] = valid ? v : -INFINITY;
  __syncthreads();
  if (t < 64) {
    float s4 = ps[t] + ps[t + 64] + ps[t + 128] + ps[t + 192];
    float m4 = fmaxf(fmaxf(pm[t], pm[t + 64]), fmaxf(pm[t + 128], pm[t + 192]));
    atomicAdd(&rsum[b * 64 + t], s4);
    atomicMax(&rmaxI[b * 64 + t], ford(m4));
  }
}

// remap edges AND build next layer's CSR (cnt pre-zeroed)
__global__ void k_remap_csr(int* __restrict__ src, int* __restrict__ dst,
                            int* __restrict__ em, const int* __restrict__ new_id,
                            int* __restrict__ cnt, int* __restrict__ csr) {
  int e = blockIdx.x * blockDim.x + threadIdx.x;
  if (e >= E_TOT) return;
  int ns = new_id[src[e]], nd = new_id[dst[e]];
  int m = em[e] && ns >= 0 && nd >= 0;
  src[e] = m ? ns : 0;
  dst[e] = m ? nd : 0;
  em[e] = m;
  if (m) {
    int pos = atomicAdd(&cnt[nd], 1);
    if (pos < MAXDEG) csr[nd * MAXDEG + pos] = e;
  }
}

__global__ void k_readout_fin(const float* __restrict__ rsum, const u32* __restrict__ rmaxI,
                              int k, float* __restrict__ r) {
  int b = blockIdx.x, c = threadIdx.x;   // 128 threads
  if (c < 64) r[b * 128 + c] += rsum[b * 64 + c] / (float)k;
  else        r[b * 128 + c] += ford_inv(rmaxI[b * 64 + (c - 64)]);
}

__global__ void k_mlp(const float* __restrict__ r,
                      const float* __restrict__ W1, const float* __restrict__ b1,
                      const float* __restrict__ W2, const float* __restrict__ b2,
                      const float* __restrict__ W3, const float* __restrict__ b3,
                      float* __restrict__ out) {
  __shared__ float v0[128], v1[64], v2[64], lgts[16];
  int b = blockIdx.x, t = threadIdx.x;   // 64 threads
  v0[t] = r[b * 128 + t];
  v0[64 + t] = r[b * 128 + 64 + t];
  __syncthreads();
  float a = b1[t];
  for (int i = 0; i < 128; ++i) a += v0[i] * W1[i * 64 + t];
  v1[t] = fmaxf(a, 0.f);
  __syncthreads();
  a = b2[t];
  for (int i = 0; i < 64; ++i) a += v1[i] * W2[i * 64 + t];
  v2[t] = fmaxf(a, 0.f);
  __syncthreads();
  if (t < 16) {
    a = b3[t];
    for (int i = 0; i < 64; ++i) a += v2[i] * W3[i * 16 + t];
    lgts[t] = a;
  }
  __syncthreads();
  if (t == 0) {
    float m = lgts[0];
    for (int j = 1; j < 16; ++j) m = fmaxf(m, lgts[j]);
    float ex[16], sum = 0.f;
    for (int j = 0; j < 16; ++j) { ex[j] = expf(lgts[j] - m); sum += ex[j]; }
    for (int j = 0; j < 16; ++j) out[b * 16 + j] = ex[j] / sum;
  }
}

extern "C" void kernel_launch(void* const* d_in, const int* in_sizes, int n_in,
                              void* d_out, int out_size, void* d_ws, size_t ws_size,
                              hipStream_t stream) {
  (void)in_sizes; (void)n_in; (void)out_size; (void)ws_size;
  const float* x  = (const float*)d_in[0];      // [NMAX, 32] f32
  const float* ea = (const float*)d_in[1];      // [E, 8]     f32
  const int*   ei = (const int*)d_in[2];        // [2, E]

  const float *gWl[3], *gbl[3], *gWr[3], *gbr[3], *gWe[3], *gatt[3], *gb[3], *pw[3];
  for (int l = 0; l < 3; ++l) {
    int p0 = 4 + 7 * l;
    gWl[l]  = (const float*)d_in[p0 + 0];
    gbl[l]  = (const float*)d_in[p0 + 1];
    gWr[l]  = (const float*)d_in[p0 + 2];
    gbr[l]  = (const float*)d_in[p0 + 3];
    gWe[l]  = (const float*)d_in[p0 + 4];
    gatt[l] = (const float*)d_in[p0 + 5];
    gb[l]   = (const float*)d_in[p0 + 6];
    pw[l]   = (const float*)d_in[25 + l];
  }
  const float* fc1W = (const float*)d_in[28];
  const float* fc1b = (const float*)d_in[29];
  const float* fc2W = (const float*)d_in[30];
  const float* fc2b = (const float*)d_in[31];
  const float* fc3W = (const float*)d_in[32];
  const float* fc3b = (const float*)d_in[33];

  // ---- workspace carve (~137 MB; fits per round-5 gate) ----
  char* w = (char*)d_ws;
  size_t off = 0;
  auto alloc = [&](size_t bytes) -> void* {
    void* p = w + off;
    off += (bytes + 255) & ~(size_t)255;
    return p;
  };
  float* hbuf = (float*)alloc((size_t)B_ * 1268 * 64 * 4); // pooled features (max K1)
  float* xl   = (float*)alloc((size_t)NMAX * 256 * 4);     // source transform [N,256]
  float* xr   = (float*)alloc((size_t)NMAX * 256 * 4);     // target transform [N,256]
  float* nacc = (float*)alloc((size_t)NMAX * 64 * 4);      // fused GAT output (pre-pool)
  int*   cnt  = (int*)alloc((size_t)NMAX * 4);             // CSR degree counters
  char*  rblk = (char*)alloc(3 * 32 * 128 * 4);            // per-layer [rsum][rmaxI] x3
  int*   csr  = (int*)alloc((size_t)NMAX * MAXDEG * 4);
  float* sbuf = (float*)alloc((size_t)NMAX * 4);
  float* rbuf = (float*)alloc(32 * 128 * 4);
  int* src    = (int*)alloc((size_t)E_TOT * 4);
  int* dst    = (int*)alloc((size_t)E_TOT * 4);
  int* em     = (int*)alloc((size_t)E_TOT * 4);
  int* new_id = (int*)alloc((size_t)NMAX * 4);
  int* perm   = (int*)alloc((size_t)32 * 1268 * 4);

  hipMemsetAsync(cnt, 0, (size_t)NMAX * 4, stream);
  hipMemsetAsync(rblk, 0, 3 * 32 * 128 * 4, stream);
  hipMemsetAsync(rbuf, 0, 32 * 128 * 4, stream);
  k_edge_init_csr<<<CDIV(E_TOT, 256), 256, 0, stream>>>(ei, src, dst, em, cnt, csr);

  const int Ns[3]    = {50688, 40576, 32480};   // B*N0, B*K1, B*K2 (all %16==0)
  const int npers[3] = {1584, 1268, 1015};
  const int ks[3]    = {1268, 1015, 812};
  const int npads[3] = {2048, 2048, 1024};

  for (int l = 0; l < 3; ++l) {
    int N = Ns[l];
    const float* hin = (l == 0) ? x : hbuf;
    float* rsum = (float*)(rblk + l * 32 * 128 * 4);
    u32* rmaxI  = (u32*)(rblk + l * 32 * 128 * 4 + 32 * 64 * 4);
    if (l == 0)
      k_transform_t<32><<<N / 16, 256, 0, stream>>>(hin, gWl[l], gbl[l], gWr[l], gbr[l], xl, xr);
    else
      k_transform_t<64><<<N / 16, 256, 0, stream>>>(hin, gWl[l], gbl[l], gWr[l], gbr[l], xl, xr);
    k_gat_fused<<<N / 4, 256, 0, stream>>>(src, cnt, csr, ea, gWe[l], gatt[l],
                                           xl, xr, gb[l], pw[l], nacc, sbuf, N);
    k_topk<<<32, 1024, 0, stream>>>(sbuf, npers[l], ks[l], npads[l], perm, new_id);
    k_gather_ro<<<dim3(32, CDIV(ks[l], 4)), 256, 0, stream>>>(nacc, sbuf, perm, hbuf,
                                                              ks[l], rsum, rmaxI);
    if (l < 2) {
      hipMemsetAsync(cnt, 0, (size_t)NMAX * 4, stream);
      k_remap_csr<<<CDIV(E_TOT, 256), 256, 0, stream>>>(src, dst, em, new_id, cnt, csr);
    }
    k_readout_fin<<<32, 128, 0, stream>>>(rsum, rmaxI, ks[l], rbuf);
  }
  k_mlp<<<32, 64, 0, stream>>>(rbuf, fc1W, fc1b, fc2W, fc2b, fc3W, fc3b, (float*)d_out);
}

// Round 15
// 535.285 us; speedup vs baseline: 1.1529x; 1.0278x over previous
//
#include <hip/hip_runtime.h>

typedef unsigned short u16;
typedef unsigned int u32;
typedef unsigned long long u64;

#define E_TOT 202752   // B*N0*DEG = 32*1584*4
#define NMAX  50688    // B*N0
#define HEADS 4
#define B_    32
#define MAXDEG 32      // Poisson(4) in-degree: P(>=32) ~ 1e-18/node — safe bucket

#define CDIV(a,b) (((a)+(b)-1)/(b))

// order-preserving float->uint map (monotonic); code 0 is below any real float's code
__device__ __forceinline__ u32 ford(float f) {
  u32 u = __float_as_uint(f);
  return (u & 0x80000000u) ? ~u : (u | 0x80000000u);
}
__device__ __forceinline__ float ford_inv(u32 u) {
  u32 b = (u & 0x80000000u) ? (u ^ 0x80000000u) : ~u;
  return __uint_as_float(b);
}

// edge arrays + CSR for layer 0 in one pass (cnt pre-zeroed)
__global__ void k_edge_init_csr(const int* __restrict__ ei, int* __restrict__ src,
                                int* __restrict__ dst, int* __restrict__ em,
                                int* __restrict__ cnt, int* __restrict__ csr) {
  int e = blockIdx.x * blockDim.x + threadIdx.x;
  if (e >= E_TOT) return;
  int s = ei[e], d = ei[E_TOT + e];
  src[e] = s;
  dst[e] = d;
  em[e] = 1;
  int pos = atomicAdd(&cnt[d], 1);
  if (pos < MAXDEG) csr[d * MAXDEG + pos] = e;
}

// ---------- node transform, 16 nodes/block, transposed-LDS x, b128 broadcast reads ----
template <int FIN>
__global__ void k_transform_t(const float* __restrict__ hin,
                              const float* __restrict__ Wl, const float* __restrict__ bl,
                              const float* __restrict__ Wr, const float* __restrict__ br,
                              float* __restrict__ xl, float* __restrict__ xr) {
  __shared__ float xs[FIN][20];
  int n0 = blockIdx.x * 16, j = threadIdx.x;   // 256 threads
  for (int t = j; t < 16 * FIN; t += 256) {
    int nd = t >> (FIN == 32 ? 5 : 6), f = t & (FIN - 1);
    xs[f][nd] = hin[(size_t)(n0 + nd) * FIN + f];
  }
  __syncthreads();
  float al[16], ar[16];
  float blv = bl[j], brv = br[j];
#pragma unroll
  for (int t = 0; t < 16; ++t) { al[t] = blv; ar[t] = brv; }
  for (int i = 0; i < FIN; ++i) {
    float wl = Wl[i * 256 + j], wr = Wr[i * 256 + j];
    float4 x0 = *(const float4*)&xs[i][0];     // broadcast b128 reads
    float4 x1 = *(const float4*)&xs[i][4];
    float4 x2 = *(const float4*)&xs[i][8];
    float4 x3 = *(const float4*)&xs[i][12];
    al[0]  += x0.x * wl; ar[0]  += x0.x * wr;
    al[1]  += x0.y * wl; ar[1]  += x0.y * wr;
    al[2]  += x0.z * wl; ar[2]  += x0.z * wr;
    al[3]  += x0.w * wl; ar[3]  += x0.w * wr;
    al[4]  += x1.x * wl; ar[4]  += x1.x * wr;
    al[5]  += x1.y * wl; ar[5]  += x1.y * wr;
    al[6]  += x1.z * wl; ar[6]  += x1.z * wr;
    al[7]  += x1.w * wl; ar[7]  += x1.w * wr;
    al[8]  += x2.x * wl; ar[8]  += x2.x * wr;
    al[9]  += x2.y * wl; ar[9]  += x2.y * wr;
    al[10] += x2.z * wl; ar[10] += x2.z * wr;
    al[11] += x2.w * wl; ar[11] += x2.w * wr;
    al[12] += x3.x * wl; ar[12] += x3.x * wr;
    al[13] += x3.y * wl; ar[13] += x3.y * wr;
    al[14] += x3.z * wl; ar[14] += x3.z * wr;
    al[15] += x3.w * wl; ar[15] += x3.w * wr;
  }
#pragma unroll
  for (int t = 0; t < 16; ++t) {
    xl[(size_t)(n0 + t) * 256 + j] = al[t];
    xr[(size_t)(n0 + t) * 256 + j] = ar[t];
  }
}

// ---------- fused GATv2: PERSISTENT grid, chunked node range per wave ----------
// grid = 2048 x 256 (4 waves/block); wave w handles nodes [w*npw, min(N,(w+1)*npw))
// per-node body identical to the proven round-10 form
__global__ void k_gat_fused(const int* __restrict__ srcv, const int* __restrict__ cnt,
                            const int* __restrict__ csr, const float* __restrict__ ea,
                            const float* __restrict__ We, const float* __restrict__ att,
                            const float* __restrict__ xl, const float* __restrict__ xr,
                            const float* __restrict__ bias, const float* __restrict__ pwv,
                            float* __restrict__ out, float* __restrict__ sc,
                            int N, int npw) {
  int wid = blockIdx.x * 4 + (threadIdx.x >> 6);
  int lane = threadIdx.x & 63;
  int cg = lane & 15;
  int cb = (lane >> 4) * 64 + cg * 4;              // this lane's 4 channels
  int n0 = wid * npw, n1 = min(N, n0 + npw);
  if (n0 >= N) return;
  // per-layer constants, hoisted once per wave
  float4 at4 = *(const float4*)(att + cb);
  float4 w0 = *(const float4*)(We + 0 * 256 + cb);
  float4 w1 = *(const float4*)(We + 1 * 256 + cb);
  float4 w2 = *(const float4*)(We + 2 * 256 + cb);
  float4 w3 = *(const float4*)(We + 3 * 256 + cb);
  float4 w4_ = *(const float4*)(We + 4 * 256 + cb);
  float4 w5 = *(const float4*)(We + 5 * 256 + cb);
  float4 w6 = *(const float4*)(We + 6 * 256 + cb);
  float4 w7 = *(const float4*)(We + 7 * 256 + cb);
  float4 bi4 = *(const float4*)(bias + cg * 4);
  float4 pw4 = *(const float4*)(pwv + cg * 4);
  float wn = pw4.x * pw4.x + pw4.y * pw4.y + pw4.z * pw4.z + pw4.w * pw4.w;
  wn += __shfl_xor(wn, 1, 64); wn += __shfl_xor(wn, 2, 64);
  wn += __shfl_xor(wn, 4, 64); wn += __shfl_xor(wn, 8, 64);
  float isq = 1.f / sqrtf(wn);

  for (int n = n0; n < n1; ++n) {
    int deg = min(cnt[n], MAXDEG);
    int e_l = 0, s_l = 0;
    if (lane < deg) { e_l = csr[n * MAXDEG + lane]; s_l = srcv[e_l]; }
    float4 xd4 = *(const float4*)(xr + (size_t)n * 256 + cb);
    float m = -INFINITY, l = 0.f;
    float ox = 0.f, oy = 0.f, oz = 0.f, ow = 0.f;
    for (int i0 = 0; i0 < deg; i0 += 4) {
      int c0 = deg - i0; if (c0 > 4) c0 = 4;       // wave-uniform
      float4 xs[4], a0[4], a1[4];
#pragma unroll
      for (int j = 0; j < 4; ++j) {
        int idx = (j < c0) ? (i0 + j) : i0;        // clamp to a safe slot
        int e = __shfl(e_l, idx, 64);
        int s = __shfl(s_l, idx, 64);
        xs[j] = *(const float4*)(xl + (size_t)s * 256 + cb);   // independent, in flight
        a0[j] = *(const float4*)(ea + (size_t)e * 8);
        a1[j] = *(const float4*)(ea + (size_t)e * 8 + 4);
      }
#pragma unroll
      for (int j = 0; j < 4; ++j) {
        if (j < c0) {
          float e0 = a0[j].x * w0.x + a0[j].y * w1.x + a0[j].z * w2.x + a0[j].w * w3.x
                   + a1[j].x * w4_.x + a1[j].y * w5.x + a1[j].z * w6.x + a1[j].w * w7.x;
          float e1 = a0[j].x * w0.y + a0[j].y * w1.y + a0[j].z * w2.y + a0[j].w * w3.y
                   + a1[j].x * w4_.y + a1[j].y * w5.y + a1[j].z * w6.y + a1[j].w * w7.y;
          float e2 = a0[j].x * w0.z + a0[j].y * w1.z + a0[j].z * w2.z + a0[j].w * w3.z
                   + a1[j].x * w4_.z + a1[j].y * w5.z + a1[j].z * w6.z + a1[j].w * w7.z;
          float e3 = a0[j].x * w0.w + a0[j].y * w1.w + a0[j].z * w2.w + a0[j].w * w3.w
                   + a1[j].x * w4_.w + a1[j].y * w5.w + a1[j].z * w6.w + a1[j].w * w7.w;
          float m0 = xs[j].x + xd4.x + e0; m0 = (m0 >= 0.f) ? m0 : 0.2f * m0;  // leaky
          float m1 = xs[j].y + xd4.y + e1; m1 = (m1 >= 0.f) ? m1 : 0.2f * m1;
          float m2 = xs[j].z + xd4.z + e2; m2 = (m2 >= 0.f) ? m2 : 0.2f * m2;
          float m3 = xs[j].w + xd4.w + e3; m3 = (m3 >= 0.f) ? m3 : 0.2f * m3;
          float v = at4.x * m0 + at4.y * m1 + at4.z * m2 + at4.w * m3;
          v += __shfl_xor(v, 1, 64);
          v += __shfl_xor(v, 2, 64);
          v += __shfl_xor(v, 4, 64);
          v += __shfl_xor(v, 8, 64);     // all 16 head-lanes hold the head logit
          float nm = fmaxf(m, v);
          float scale = __expf(m - nm);  // exp(-inf - x) = 0 handles first edge
          float p = __expf(v - nm);
          ox = ox * scale + p * xs[j].x;
          oy = oy * scale + p * xs[j].y;
          oz = oz * scale + p * xs[j].z;
          ow = ow * scale + p * xs[j].w;
          l = l * scale + p;
          m = nm;
        }
      }
    }
    // per-head y = O/den, then 0.25 * head-sum  (deg==0 -> l=0 -> y=0, matches ref)
    float inv = 0.25f / fmaxf(l, 1e-16f);
    float r0 = ox * inv, r1 = oy * inv, r2 = oz * inv, r3 = ow * inv;
    r0 += __shfl_xor(r0, 16, 64); r0 += __shfl_xor(r0, 32, 64);
    r1 += __shfl_xor(r1, 16, 64); r1 += __shfl_xor(r1, 32, 64);
    r2 += __shfl_xor(r2, 16, 64); r2 += __shfl_xor(r2, 32, 64);
    r3 += __shfl_xor(r3, 16, 64); r3 += __shfl_xor(r3, 32, 64);
    float rr0 = fmaxf(r0 + bi4.x, 0.f), rr1 = fmaxf(r1 + bi4.y, 0.f);
    float rr2 = fmaxf(r2 + bi4.z, 0.f), rr3 = fmaxf(r3 + bi4.w, 0.f);
    if (lane < 16) *(float4*)(out + (size_t)n * 64 + cg * 4) = float4{rr0, rr1, rr2, rr3};
    // topk score: s = tanh(h.w / ||w||)
    float dot = rr0 * pw4.x + rr1 * pw4.y + rr2 * pw4.z + rr3 * pw4.w;
    dot += __shfl_xor(dot, 1, 64);
    dot += __shfl_xor(dot, 2, 64);
    dot += __shfl_xor(dot, 4, 64);
    dot += __shfl_xor(dot, 8, 64);
    if (lane == 0) sc[n] = tanhf(dot * isq);
  }
}

// stable descending sort per graph — u64 keys (ford(score)<<32 | ~idx), bitonic <=2048
__global__ __launch_bounds__(1024) void k_topk(const float* __restrict__ s, int n_per,
                                               int k, int npad,
                                               int* __restrict__ perm, int* __restrict__ new_id) {
  __shared__ u64 kv[2048];
  int b = blockIdx.x, tid = threadIdx.x;
  int base = b * n_per;
  for (int i = tid; i < n_per; i += 1024) new_id[base + i] = -1;
  for (int i = tid; i < npad; i += 1024) {
    u32 sk = (i < n_per) ? ford(s[base + i]) : 0u;   // pad key 0: below every real code
    kv[i] = ((u64)sk << 32) | (u32)(0xFFFFFFFFu - (u32)i);   // tie -> lower idx first
  }
  __syncthreads();
  for (int kk = 2; kk <= npad; kk <<= 1) {
    for (int j = kk >> 1; j > 0; j >>= 1) {
      for (int i = tid; i < npad; i += 1024) {
        int ixj = i ^ j;
        if (ixj > i) {
          u64 a = kv[i], c = kv[ixj];
          bool after = a < c;                        // descending order
          bool doswap = ((i & kk) == 0) ? after : !after;
          if (doswap) { kv[i] = c; kv[ixj] = a; }
        }
      }
      __syncthreads();
    }
  }
  for (int r = tid; r < k; r += 1024) {
    int old = (int)(0xFFFFFFFFu - (u32)(kv[r] & 0xFFFFFFFFu));
    perm[b * k + r] = base + old;
    new_id[base + old] = b * k + r;
  }
}

// fused gather + readout partials: grid (B, ceil(k/4)), 256 thr (4 nodes/block)
__global__ void k_gather_ro(const float* __restrict__ hin, const float* __restrict__ s,
                            const int* __restrict__ perm, float* __restrict__ hout,
                            int k, float* __restrict__ rsum, u32* __restrict__ rmaxI) {
  __shared__ float ps[256], pm[256];
  int b = blockIdx.x, t = threadIdx.x;
  int i = blockIdx.y * 4 + (t >> 6);            // local kept-node index
  int c = t & 63;
  bool valid = i < k;
  float v = 0.f;
  if (valid) {
    int g = perm[b * k + i];
    v = hin[(size_t)g * 64 + c] * s[g];
    hout[((size_t)b * k + i) * 64 + c] = v;
  }
  ps[t] = valid ? v : 0.f;
  pm[t] = valid ? v : -INFINITY;
  __syncthreads();
  if (t < 64) {
    float s4 = ps[t] + ps[t + 64] + ps[t + 128] + ps[t + 192];
    float m4 = fmaxf(fmaxf(pm[t], pm[t + 64]), fmaxf(pm[t + 128], pm[t + 192]));
    atomicAdd(&rsum[b * 64 + t], s4);
    atomicMax(&rmaxI[b * 64 + t], ford(m4));
  }
}

// remap edges AND build next layer's CSR (cnt pre-zeroed)
__global__ void k_remap_csr(int* __restrict__ src, int* __restrict__ dst,
                            int* __restrict__ em, const int* __restrict__ new_id,
                            int* __restrict__ cnt, int* __restrict__ csr) {
  int e = blockIdx.x * blockDim.x + threadIdx.x;
  if (e >= E_TOT) return;
  int ns = new_id[src[e]], nd = new_id[dst[e]];
  int m = em[e] && ns >= 0 && nd >= 0;
  src[e] = m ? ns : 0;
  dst[e] = m ? nd : 0;
  em[e] = m;
  if (m) {
    int pos = atomicAdd(&cnt[nd], 1);
    if (pos < MAXDEG) csr[nd * MAXDEG + pos] = e;
  }
}

// MLP with readout finalization folded in: reads [rsum|rmaxI] x 3 layers directly
__global__ void k_mlp(const char* __restrict__ rblk,
                      const float* __restrict__ W1, const float* __restrict__ b1,
                      const float* __restrict__ W2, const float* __restrict__ b2,
                      const float* __restrict__ W3, const float* __restrict__ b3,
                      float* __restrict__ out) {
  __shared__ float v0[128], v1[64], v2[64], lgts[16];
  int b = blockIdx.x, t = threadIdx.x;   // 64 threads
  const float* rs0 = (const float*)rblk;
  const u32*   rm0 = (const u32*)(rblk + 32 * 64 * 4);
  const float* rs1 = (const float*)(rblk + 32 * 128 * 4);
  const u32*   rm1 = (const u32*)(rblk + 32 * 128 * 4 + 32 * 64 * 4);
  const float* rs2 = (const float*)(rblk + 2 * 32 * 128 * 4);
  const u32*   rm2 = (const u32*)(rblk + 2 * 32 * 128 * 4 + 32 * 64 * 4);
  v0[t] = rs0[b * 64 + t] / 1268.f + rs1[b * 64 + t] / 1015.f + rs2[b * 64 + t] / 812.f;
  v0[64 + t] = ford_inv(rm0[b * 64 + t]) + ford_inv(rm1[b * 64 + t]) + ford_inv(rm2[b * 64 + t]);
  __syncthreads();
  float a = b1[t];
  for (int i = 0; i < 128; ++i) a += v0[i] * W1[i * 64 + t];
  v1[t] = fmaxf(a, 0.f);
  __syncthreads();
  a = b2[t];
  for (int i = 0; i < 64; ++i) a += v1[i] * W2[i * 64 + t];
  v2[t] = fmaxf(a, 0.f);
  __syncthreads();
  if (t < 16) {
    a = b3[t];
    for (int i = 0; i < 64; ++i) a += v2[i] * W3[i * 16 + t];
    lgts[t] = a;
  }
  __syncthreads();
  if (t == 0) {
    float m = lgts[0];
    for (int j = 1; j < 16; ++j) m = fmaxf(m, lgts[j]);
    float ex[16], sum = 0.f;
    for (int j = 0; j < 16; ++j) { ex[j] = expf(lgts[j] - m); sum += ex[j]; }
    for (int j = 0; j < 16; ++j) out[b * 16 + j] = ex[j] / sum;
  }
}

extern "C" void kernel_launch(void* const* d_in, const int* in_sizes, int n_in,
                              void* d_out, int out_size, void* d_ws, size_t ws_size,
                              hipStream_t stream) {
  (void)in_sizes; (void)n_in; (void)out_size; (void)ws_size;
  const float* x  = (const float*)d_in[0];      // [NMAX, 32] f32
  const float* ea = (const float*)d_in[1];      // [E, 8]     f32
  const int*   ei = (const int*)d_in[2];        // [2, E]

  const float *gWl[3], *gbl[3], *gWr[3], *gbr[3], *gWe[3], *gatt[3], *gb[3], *pw[3];
  for (int l = 0; l < 3; ++l) {
    int p0 = 4 + 7 * l;
    gWl[l]  = (const float*)d_in[p0 + 0];
    gbl[l]  = (const float*)d_in[p0 + 1];
    gWr[l]  = (const float*)d_in[p0 + 2];
    gbr[l]  = (const float*)d_in[p0 + 3];
    gWe[l]  = (const float*)d_in[p0 + 4];
    gatt[l] = (const float*)d_in[p0 + 5];
    gb[l]   = (const float*)d_in[p0 + 6];
    pw[l]   = (const float*)d_in[25 + l];
  }
  const float* fc1W = (const float*)d_in[28];
  const float* fc1b = (const float*)d_in[29];
  const float* fc2W = (const float*)d_in[30];
  const float* fc2b = (const float*)d_in[31];
  const float* fc3W = (const float*)d_in[32];
  const float* fc3b = (const float*)d_in[33];

  // ---- workspace carve (~137 MB; fits per round-5 gate) ----
  char* w = (char*)d_ws;
  size_t off = 0;
  auto alloc = [&](size_t bytes) -> void* {
    void* p = w + off;
    off += (bytes + 255) & ~(size_t)255;
    return p;
  };
  float* hbuf = (float*)alloc((size_t)B_ * 1268 * 64 * 4); // pooled features (max K1)
  float* xl   = (float*)alloc((size_t)NMAX * 256 * 4);     // source transform [N,256]
  float* xr   = (float*)alloc((size_t)NMAX * 256 * 4);     // target transform [N,256]
  float* nacc = (float*)alloc((size_t)NMAX * 64 * 4);      // fused GAT output (pre-pool)
  int*   cnt  = (int*)alloc((size_t)NMAX * 4);             // CSR degree counters
  char*  rblk = (char*)alloc(3 * 32 * 128 * 4);            // per-layer [rsum][rmaxI] x3
  int*   csr  = (int*)alloc((size_t)NMAX * MAXDEG * 4);
  float* sbuf = (float*)alloc((size_t)NMAX * 4);
  int* src    = (int*)alloc((size_t)E_TOT * 4);
  int* dst    = (int*)alloc((size_t)E_TOT * 4);
  int* em     = (int*)alloc((size_t)E_TOT * 4);
  int* new_id = (int*)alloc((size_t)NMAX * 4);
  int* perm   = (int*)alloc((size_t)32 * 1268 * 4);

  hipMemsetAsync(cnt, 0, (size_t)NMAX * 4, stream);
  hipMemsetAsync(rblk, 0, 3 * 32 * 128 * 4, stream);
  k_edge_init_csr<<<CDIV(E_TOT, 256), 256, 0, stream>>>(ei, src, dst, em, cnt, csr);

  const int Ns[3]    = {50688, 40576, 32480};   // B*N0, B*K1, B*K2 (all %16==0)
  const int npers[3] = {1584, 1268, 1015};
  const int ks[3]    = {1268, 1015, 812};
  const int npads[3] = {2048, 2048, 1024};
  const int GAT_BLOCKS = 2048;                  // persistent grid: 8192 waves

  for (int l = 0; l < 3; ++l) {
    int N = Ns[l];
    const float* hin = (l == 0) ? x : hbuf;
    float* rsum = (float*)(rblk + l * 32 * 128 * 4);
    u32* rmaxI  = (u32*)(rblk + l * 32 * 128 * 4 + 32 * 64 * 4);
    if (l == 0)
      k_transform_t<32><<<N / 16, 256, 0, stream>>>(hin, gWl[l], gbl[l], gWr[l], gbr[l], xl, xr);
    else
      k_transform_t<64><<<N / 16, 256, 0, stream>>>(hin, gWl[l], gbl[l], gWr[l], gbr[l], xl, xr);
    int npw = CDIV(N, GAT_BLOCKS * 4);
    k_gat_fused<<<GAT_BLOCKS, 256, 0, stream>>>(src, cnt, csr, ea, gWe[l], gatt[l],
                                                xl, xr, gb[l], pw[l], nacc, sbuf, N, npw);
    k_topk<<<32, 1024, 0, stream>>>(sbuf, npers[l], ks[l], npads[l], perm, new_id);
    k_gather_ro<<<dim3(32, CDIV(ks[l], 4)), 256, 0, stream>>>(nacc, sbuf, perm, hbuf,
                                                              ks[l], rsum, rmaxI);
    if (l < 2) {
      hipMemsetAsync(cnt, 0, (size_t)NMAX * 4, stream);
      k_remap_csr<<<CDIV(E_TOT, 256), 256, 0, stream>>>(src, dst, em, new_id, cnt, csr);
    }
  }
  k_mlp<<<32, 64, 0, stream>>>(rblk, fc1W, fc1b, fc2W, fc2b, fc3W, fc3b, (float*)d_out);
}

// Round 16
// 519.830 us; speedup vs baseline: 1.1872x; 1.0297x over previous
//
#include <hip/hip_runtime.h>

typedef unsigned short u16;
typedef unsigned int u32;
typedef unsigned long long u64;

#define E_TOT 202752   // B*N0*DEG = 32*1584*4
#define NMAX  50688    // B*N0
#define HEADS 4
#define B_    32
#define MAXDEG 32      // Poisson(4) in-degree: P(>=32) ~ 1e-18/node — safe bucket

#define CDIV(a,b) (((a)+(b)-1)/(b))

// order-preserving float->uint map (monotonic); code 0 is below any real float's code
__device__ __forceinline__ u32 ford(float f) {
  u32 u = __float_as_uint(f);
  return (u & 0x80000000u) ? ~u : (u | 0x80000000u);
}
__device__ __forceinline__ float ford_inv(u32 u) {
  u32 b = (u & 0x80000000u) ? (u ^ 0x80000000u) : ~u;
  return __uint_as_float(b);
}

// DPP row-rotate (16-lane row) move; CTRL = 0x120 | n for row_ror:n
template <int CTRL>
__device__ __forceinline__ float dpp_mov(float x) {
  return __int_as_float(__builtin_amdgcn_mov_dpp(__float_as_int(x), CTRL, 0xF, 0xF, false));
}
// sum over each 16-lane row via VALU-pipe rotations (no DS pipe on the hot path)
__device__ __forceinline__ float row16_sum(float v) {
  v += dpp_mov<0x121>(v);   // row_ror:1
  v += dpp_mov<0x122>(v);   // row_ror:2
  v += dpp_mov<0x124>(v);   // row_ror:4
  v += dpp_mov<0x128>(v);   // row_ror:8
  return v;
}

// edge arrays + CSR for layer 0 in one pass (cnt pre-zeroed)
__global__ void k_edge_init_csr(const int* __restrict__ ei, int* __restrict__ src,
                                int* __restrict__ dst, int* __restrict__ em,
                                int* __restrict__ cnt, int* __restrict__ csr) {
  int e = blockIdx.x * blockDim.x + threadIdx.x;
  if (e >= E_TOT) return;
  int s = ei[e], d = ei[E_TOT + e];
  src[e] = s;
  dst[e] = d;
  em[e] = 1;
  int pos = atomicAdd(&cnt[d], 1);
  if (pos < MAXDEG) csr[d * MAXDEG + pos] = e;
}

// ---------- node transform, 16 nodes/block, transposed-LDS x, b128 broadcast reads ----
template <int FIN>
__global__ void k_transform_t(const float* __restrict__ hin,
                              const float* __restrict__ Wl, const float* __restrict__ bl,
                              const float* __restrict__ Wr, const float* __restrict__ br,
                              float* __restrict__ xl, float* __restrict__ xr) {
  __shared__ float xs[FIN][20];
  int n0 = blockIdx.x * 16, j = threadIdx.x;   // 256 threads
  for (int t = j; t < 16 * FIN; t += 256) {
    int nd = t >> (FIN == 32 ? 5 : 6), f = t & (FIN - 1);
    xs[f][nd] = hin[(size_t)(n0 + nd) * FIN + f];
  }
  __syncthreads();
  float al[16], ar[16];
  float blv = bl[j], brv = br[j];
#pragma unroll
  for (int t = 0; t < 16; ++t) { al[t] = blv; ar[t] = brv; }
  for (int i = 0; i < FIN; ++i) {
    float wl = Wl[i * 256 + j], wr = Wr[i * 256 + j];
    float4 x0 = *(const float4*)&xs[i][0];     // broadcast b128 reads
    float4 x1 = *(const float4*)&xs[i][4];
    float4 x2 = *(const float4*)&xs[i][8];
    float4 x3 = *(const float4*)&xs[i][12];
    al[0]  += x0.x * wl; ar[0]  += x0.x * wr;
    al[1]  += x0.y * wl; ar[1]  += x0.y * wr;
    al[2]  += x0.z * wl; ar[2]  += x0.z * wr;
    al[3]  += x0.w * wl; ar[3]  += x0.w * wr;
    al[4]  += x1.x * wl; ar[4]  += x1.x * wr;
    al[5]  += x1.y * wl; ar[5]  += x1.y * wr;
    al[6]  += x1.z * wl; ar[6]  += x1.z * wr;
    al[7]  += x1.w * wl; ar[7]  += x1.w * wr;
    al[8]  += x2.x * wl; ar[8]  += x2.x * wr;
    al[9]  += x2.y * wl; ar[9]  += x2.y * wr;
    al[10] += x2.z * wl; ar[10] += x2.z * wr;
    al[11] += x2.w * wl; ar[11] += x2.w * wr;
    al[12] += x3.x * wl; ar[12] += x3.x * wr;
    al[13] += x3.y * wl; ar[13] += x3.y * wr;
    al[14] += x3.z * wl; ar[14] += x3.z * wr;
    al[15] += x3.w * wl; ar[15] += x3.w * wr;
  }
#pragma unroll
  for (int t = 0; t < 16; ++t) {
    xl[(size_t)(n0 + t) * 256 + j] = al[t];
    xr[(size_t)(n0 + t) * 256 + j] = ar[t];
  }
}

// ---------- fused GATv2: persistent grid, DPP row-rotate logit reduction ----------
__global__ void k_gat_fused(const int* __restrict__ srcv, const int* __restrict__ cnt,
                            const int* __restrict__ csr, const float* __restrict__ ea,
                            const float* __restrict__ We, const float* __restrict__ att,
                            const float* __restrict__ xl, const float* __restrict__ xr,
                            const float* __restrict__ bias, const float* __restrict__ pwv,
                            float* __restrict__ out, float* __restrict__ sc,
                            int N, int npw) {
  int wid = blockIdx.x * 4 + (threadIdx.x >> 6);
  int lane = threadIdx.x & 63;
  int cg = lane & 15;
  int cb = (lane >> 4) * 64 + cg * 4;              // this lane's 4 channels
  int n0 = wid * npw, n1 = min(N, n0 + npw);
  if (n0 >= N) return;
  // per-layer constants, hoisted once per wave
  float4 at4 = *(const float4*)(att + cb);
  float4 w0 = *(const float4*)(We + 0 * 256 + cb);
  float4 w1 = *(const float4*)(We + 1 * 256 + cb);
  float4 w2 = *(const float4*)(We + 2 * 256 + cb);
  float4 w3 = *(const float4*)(We + 3 * 256 + cb);
  float4 w4_ = *(const float4*)(We + 4 * 256 + cb);
  float4 w5 = *(const float4*)(We + 5 * 256 + cb);
  float4 w6 = *(const float4*)(We + 6 * 256 + cb);
  float4 w7 = *(const float4*)(We + 7 * 256 + cb);
  float4 bi4 = *(const float4*)(bias + cg * 4);
  float4 pw4 = *(const float4*)(pwv + cg * 4);
  float wn = pw4.x * pw4.x + pw4.y * pw4.y + pw4.z * pw4.z + pw4.w * pw4.w;
  wn += __shfl_xor(wn, 1, 64); wn += __shfl_xor(wn, 2, 64);
  wn += __shfl_xor(wn, 4, 64); wn += __shfl_xor(wn, 8, 64);
  float isq = 1.f / sqrtf(wn);

  for (int n = n0; n < n1; ++n) {
    int deg = min(cnt[n], MAXDEG);
    int e_l = 0, s_l = 0;
    if (lane < deg) { e_l = csr[n * MAXDEG + lane]; s_l = srcv[e_l]; }
    float4 xd4 = *(const float4*)(xr + (size_t)n * 256 + cb);
    float m = -INFINITY, l = 0.f;
    float ox = 0.f, oy = 0.f, oz = 0.f, ow = 0.f;
    for (int i0 = 0; i0 < deg; i0 += 4) {
      int c0 = deg - i0; if (c0 > 4) c0 = 4;       // wave-uniform
      float4 xs[4], a0[4], a1[4];
#pragma unroll
      for (int j = 0; j < 4; ++j) {
        int idx = (j < c0) ? (i0 + j) : i0;        // clamp to a safe slot
        int e = __shfl(e_l, idx, 64);
        int s = __shfl(s_l, idx, 64);
        xs[j] = *(const float4*)(xl + (size_t)s * 256 + cb);   // independent, in flight
        a0[j] = *(const float4*)(ea + (size_t)e * 8);
        a1[j] = *(const float4*)(ea + (size_t)e * 8 + 4);
      }
#pragma unroll
      for (int j = 0; j < 4; ++j) {
        if (j < c0) {
          float e0 = a0[j].x * w0.x + a0[j].y * w1.x + a0[j].z * w2.x + a0[j].w * w3.x
                   + a1[j].x * w4_.x + a1[j].y * w5.x + a1[j].z * w6.x + a1[j].w * w7.x;
          float e1 = a0[j].x * w0.y + a0[j].y * w1.y + a0[j].z * w2.y + a0[j].w * w3.y
                   + a1[j].x * w4_.y + a1[j].y * w5.y + a1[j].z * w6.y + a1[j].w * w7.y;
          float e2 = a0[j].x * w0.z + a0[j].y * w1.z + a0[j].z * w2.z + a0[j].w * w3.z
                   + a1[j].x * w4_.z + a1[j].y * w5.z + a1[j].z * w6.z + a1[j].w * w7.z;
          float e3 = a0[j].x * w0.w + a0[j].y * w1.w + a0[j].z * w2.w + a0[j].w * w3.w
                   + a1[j].x * w4_.w + a1[j].y * w5.w + a1[j].z * w6.w + a1[j].w * w7.w;
          float m0 = xs[j].x + xd4.x + e0; m0 = (m0 >= 0.f) ? m0 : 0.2f * m0;  // leaky
          float m1 = xs[j].y + xd4.y + e1; m1 = (m1 >= 0.f) ? m1 : 0.2f * m1;
          float m2 = xs[j].z + xd4.z + e2; m2 = (m2 >= 0.f) ? m2 : 0.2f * m2;
          float m3 = xs[j].w + xd4.w + e3; m3 = (m3 >= 0.f) ? m3 : 0.2f * m3;
          float v = at4.x * m0 + at4.y * m1 + at4.z * m2 + at4.w * m3;
          v = row16_sum(v);              // 16-lane head reduction on the VALU pipe (DPP)
          float nm = fmaxf(m, v);
          float scale = __expf(m - nm);  // exp(-inf - x) = 0 handles first edge
          float p = __expf(v - nm);
          ox = ox * scale + p * xs[j].x;
          oy = oy * scale + p * xs[j].y;
          oz = oz * scale + p * xs[j].z;
          ow = ow * scale + p * xs[j].w;
          l = l * scale + p;
          m = nm;
        }
      }
    }
    // per-head y = O/den, then 0.25 * head-sum  (deg==0 -> l=0 -> y=0, matches ref)
    float inv = 0.25f / fmaxf(l, 1e-16f);
    float r0 = ox * inv, r1 = oy * inv, r2 = oz * inv, r3 = ow * inv;
    r0 += __shfl_xor(r0, 16, 64); r0 += __shfl_xor(r0, 32, 64);
    r1 += __shfl_xor(r1, 16, 64); r1 += __shfl_xor(r1, 32, 64);
    r2 += __shfl_xor(r2, 16, 64); r2 += __shfl_xor(r2, 32, 64);
    r3 += __shfl_xor(r3, 16, 64); r3 += __shfl_xor(r3, 32, 64);
    float rr0 = fmaxf(r0 + bi4.x, 0.f), rr1 = fmaxf(r1 + bi4.y, 0.f);
    float rr2 = fmaxf(r2 + bi4.z, 0.f), rr3 = fmaxf(r3 + bi4.w, 0.f);
    if (lane < 16) *(float4*)(out + (size_t)n * 64 + cg * 4) = float4{rr0, rr1, rr2, rr3};
    // topk score: s = tanh(h.w / ||w||)
    float dot = rr0 * pw4.x + rr1 * pw4.y + rr2 * pw4.z + rr3 * pw4.w;
    dot += __shfl_xor(dot, 1, 64);
    dot += __shfl_xor(dot, 2, 64);
    dot += __shfl_xor(dot, 4, 64);
    dot += __shfl_xor(dot, 8, 64);
    if (lane == 0) sc[n] = tanhf(dot * isq);
  }
}

// stable descending sort per graph — u64 keys (ford(score)<<32 | ~idx), bitonic <=2048
__global__ __launch_bounds__(1024) void k_topk(const float* __restrict__ s, int n_per,
                                               int k, int npad,
                                               int* __restrict__ perm, int* __restrict__ new_id) {
  __shared__ u64 kv[2048];
  int b = blockIdx.x, tid = threadIdx.x;
  int base = b * n_per;
  for (int i = tid; i < n_per; i += 1024) new_id[base + i] = -1;
  for (int i = tid; i < npad; i += 1024) {
    u32 sk = (i < n_per) ? ford(s[base + i]) : 0u;   // pad key 0: below every real code
    kv[i] = ((u64)sk << 32) | (u32)(0xFFFFFFFFu - (u32)i);   // tie -> lower idx first
  }
  __syncthreads();
  for (int kk = 2; kk <= npad; kk <<= 1) {
    for (int j = kk >> 1; j > 0; j >>= 1) {
      for (int i = tid; i < npad; i += 1024) {
        int ixj = i ^ j;
        if (ixj > i) {
          u64 a = kv[i], c = kv[ixj];
          bool after = a < c;                        // descending order
          bool doswap = ((i & kk) == 0) ? after : !after;
          if (doswap) { kv[i] = c; kv[ixj] = a; }
        }
      }
      __syncthreads();
    }
  }
  for (int r = tid; r < k; r += 1024) {
    int old = (int)(0xFFFFFFFFu - (u32)(kv[r] & 0xFFFFFFFFu));
    perm[b * k + r] = base + old;
    new_id[base + old] = b * k + r;
  }
}

// fused gather + readout partials: grid (B, ceil(k/4)), 256 thr (4 nodes/block)
__global__ void k_gather_ro(const float* __restrict__ hin, const float* __restrict__ s,
                            const int* __restrict__ perm, float* __restrict__ hout,
                            int k, float* __restrict__ rsum, u32* __restrict__ rmaxI) {
  __shared__ float ps[256], pm[256];
  int b = blockIdx.x, t = threadIdx.x;
  int i = blockIdx.y * 4 + (t >> 6);            // local kept-node index
  int c = t & 63;
  bool valid = i < k;
  float v = 0.f;
  if (valid) {
    int g = perm[b * k + i];
    v = hin[(size_t)g * 64 + c] * s[g];
    hout[((size_t)b * k + i) * 64 + c] = v;
  }
  ps[t] = valid ? v : 0.f;
  pm[t] = valid ? v : -INFINITY;
  __syncthreads();
  if (t < 64) {
    float s4 = ps[t] + ps[t + 64] + ps[t + 128] + ps[t + 192];
    float m4 = fmaxf(fmaxf(pm[t], pm[t + 64]), fmaxf(pm[t + 128], pm[t + 192]));
    atomicAdd(&rsum[b * 64 + t], s4);
    atomicMax(&rmaxI[b * 64 + t], ford(m4));
  }
}

// remap edges AND build next layer's CSR (cnt pre-zeroed)
__global__ void k_remap_csr(int* __restrict__ src, int* __restrict__ dst,
                            int* __restrict__ em, const int* __restrict__ new_id,
                            int* __restrict__ cnt, int* __restrict__ csr) {
  int e = blockIdx.x * blockDim.x + threadIdx.x;
  if (e >= E_TOT) return;
  int ns = new_id[src[e]], nd = new_id[dst[e]];
  int m = em[e] && ns >= 0 && nd >= 0;
  src[e] = m ? ns : 0;
  dst[e] = m ? nd : 0;
  em[e] = m;
  if (m) {
    int pos = atomicAdd(&cnt[nd], 1);
    if (pos < MAXDEG) csr[nd * MAXDEG + pos] = e;
  }
}

// MLP with readout finalization folded in: reads [rsum|rmaxI] x 3 layers directly
__global__ void k_mlp(const char* __restrict__ rblk,
                      const float* __restrict__ W1, const float* __restrict__ b1,
                      const float* __restrict__ W2, const float* __restrict__ b2,
                      const float* __restrict__ W3, const float* __restrict__ b3,
                      float* __restrict__ out) {
  __shared__ float v0[128], v1[64], v2[64], lgts[16];
  int b = blockIdx.x, t = threadIdx.x;   // 64 threads
  const float* rs0 = (const float*)rblk;
  const u32*   rm0 = (const u32*)(rblk + 32 * 64 * 4);
  const float* rs1 = (const float*)(rblk + 32 * 128 * 4);
  const u32*   rm1 = (const u32*)(rblk + 32 * 128 * 4 + 32 * 64 * 4);
  const float* rs2 = (const float*)(rblk + 2 * 32 * 128 * 4);
  const u32*   rm2 = (const u32*)(rblk + 2 * 32 * 128 * 4 + 32 * 64 * 4);
  v0[t] = rs0[b * 64 + t] / 1268.f + rs1[b * 64 + t] / 1015.f + rs2[b * 64 + t] / 812.f;
  v0[64 + t] = ford_inv(rm0[b * 64 + t]) + ford_inv(rm1[b * 64 + t]) + ford_inv(rm2[b * 64 + t]);
  __syncthreads();
  float a = b1[t];
  for (int i = 0; i < 128; ++i) a += v0[i] * W1[i * 64 + t];
  v1[t] = fmaxf(a, 0.f);
  __syncthreads();
  a = b2[t];
  for (int i = 0; i < 64; ++i) a += v1[i] * W2[i * 64 + t];
  v2[t] = fmaxf(a, 0.f);
  __syncthreads();
  if (t < 16) {
    a = b3[t];
    for (int i = 0; i < 64; ++i) a += v2[i] * W3[i * 16 + t];
    lgts[t] = a;
  }
  __syncthreads();
  if (t == 0) {
    float m = lgts[0];
    for (int j = 1; j < 16; ++j) m = fmaxf(m, lgts[j]);
    float ex[16], sum = 0.f;
    for (int j = 0; j < 16; ++j) { ex[j] = expf(lgts[j] - m); sum += ex[j]; }
    for (int j = 0; j < 16; ++j) out[b * 16 + j] = ex[j] / sum;
  }
}

extern "C" void kernel_launch(void* const* d_in, const int* in_sizes, int n_in,
                              void* d_out, int out_size, void* d_ws, size_t ws_size,
                              hipStream_t stream) {
  (void)in_sizes; (void)n_in; (void)out_size; (void)ws_size;
  const float* x  = (const float*)d_in[0];      // [NMAX, 32] f32
  const float* ea = (const float*)d_in[1];      // [E, 8]     f32
  const int*   ei = (const int*)d_in[2];        // [2, E]

  const float *gWl[3], *gbl[3], *gWr[3], *gbr[3], *gWe[3], *gatt[3], *gb[3], *pw[3];
  for (int l = 0; l < 3; ++l) {
    int p0 = 4 + 7 * l;
    gWl[l]  = (const float*)d_in[p0 + 0];
    gbl[l]  = (const float*)d_in[p0 + 1];
    gWr[l]  = (const float*)d_in[p0 + 2];
    gbr[l]  = (const float*)d_in[p0 + 3];
    gWe[l]  = (const float*)d_in[p0 + 4];
    gatt[l] = (const float*)d_in[p0 + 5];
    gb[l]   = (const float*)d_in[p0 + 6];
    pw[l]   = (const float*)d_in[25 + l];
  }
  const float* fc1W = (const float*)d_in[28];
  const float* fc1b = (const float*)d_in[29];
  const float* fc2W = (const float*)d_in[30];
  const float* fc2b = (const float*)d_in[31];
  const float* fc3W = (const float*)d_in[32];
  const float* fc3b = (const float*)d_in[33];

  // ---- workspace carve (~137 MB; fits per round-5 gate) ----
  char* w = (char*)d_ws;
  size_t off = 0;
  auto alloc = [&](size_t bytes) -> void* {
    void* p = w + off;
    off += (bytes + 255) & ~(size_t)255;
    return p;
  };
  float* hbuf = (float*)alloc((size_t)B_ * 1268 * 64 * 4); // pooled features (max K1)
  float* xl   = (float*)alloc((size_t)NMAX * 256 * 4);     // source transform [N,256]
  float* xr   = (float*)alloc((size_t)NMAX * 256 * 4);     // target transform [N,256]
  float* nacc = (float*)alloc((size_t)NMAX * 64 * 4);      // fused GAT output (pre-pool)
  int*   cnt  = (int*)alloc((size_t)NMAX * 4);             // CSR degree counters
  char*  rblk = (char*)alloc(3 * 32 * 128 * 4);            // per-layer [rsum][rmaxI] x3
  int*   csr  = (int*)alloc((size_t)NMAX * MAXDEG * 4);
  float* sbuf = (float*)alloc((size_t)NMAX * 4);
  int* src    = (int*)alloc((size_t)E_TOT * 4);
  int* dst    = (int*)alloc((size_t)E_TOT * 4);
  int* em     = (int*)alloc((size_t)E_TOT * 4);
  int* new_id = (int*)alloc((size_t)NMAX * 4);
  int* perm   = (int*)alloc((size_t)32 * 1268 * 4);

  hipMemsetAsync(cnt, 0, (size_t)NMAX * 4, stream);
  hipMemsetAsync(rblk, 0, 3 * 32 * 128 * 4, stream);
  k_edge_init_csr<<<CDIV(E_TOT, 256), 256, 0, stream>>>(ei, src, dst, em, cnt, csr);

  const int Ns[3]    = {50688, 40576, 32480};   // B*N0, B*K1, B*K2 (all %16==0)
  const int npers[3] = {1584, 1268, 1015};
  const int ks[3]    = {1268, 1015, 812};
  const int npads[3] = {2048, 2048, 1024};
  const int GAT_BLOCKS = 2048;                  // persistent grid: 8192 waves

  for (int l = 0; l < 3; ++l) {
    int N = Ns[l];
    const float* hin = (l == 0) ? x : hbuf;
    float* rsum = (float*)(rblk + l * 32 * 128 * 4);
    u32* rmaxI  = (u32*)(rblk + l * 32 * 128 * 4 + 32 * 64 * 4);
    if (l == 0)
      k_transform_t<32><<<N / 16, 256, 0, stream>>>(hin, gWl[l], gbl[l], gWr[l], gbr[l], xl, xr);
    else
      k_transform_t<64><<<N / 16, 256, 0, stream>>>(hin, gWl[l], gbl[l], gWr[l], gbr[l], xl, xr);
    int npw = CDIV(N, GAT_BLOCKS * 4);
    k_gat_fused<<<GAT_BLOCKS, 256, 0, stream>>>(src, cnt, csr, ea, gWe[l], gatt[l],
                                                xl, xr, gb[l], pw[l], nacc, sbuf, N, npw);
    k_topk<<<32, 1024, 0, stream>>>(sbuf, npers[l], ks[l], npads[l], perm, new_id);
    k_gather_ro<<<dim3(32, CDIV(ks[l], 4)), 256, 0, stream>>>(nacc, sbuf, perm, hbuf,
                                                              ks[l], rsum, rmaxI);
    if (l < 2) {
      hipMemsetAsync(cnt, 0, (size_t)NMAX * 4, stream);
      k_remap_csr<<<CDIV(E_TOT, 256), 256, 0, stream>>>(src, dst, em, new_id, cnt, csr);
    }
  }
  k_mlp<<<32, 64, 0, stream>>>(rblk, fc1W, fc1b, fc2W, fc2b, fc3W, fc3b, (float*)d_out);
}